// Round 6
// baseline (2170.413 us; speedup 1.0000x reference)
//
#include <hip/hip_runtime.h>
#include <hip/hip_bf16.h>

#define NLAYERS 6
#define B_ 4
#define L_ 1024
#define DM_ 512
#define DI_ 1024
#define NH_ 16
#define HD_ 64
#define NS_ 16
#define CONVD_ 1056
#define DPROJ_ 2096
#define DFF_ 2048
#define ROWS_ (B_*L_)
#define EPS_ 1e-5f
#define NCHUNK_ 16
#define CLEN_ 64

typedef __bf16 bfx8 __attribute__((ext_vector_type(8)));
typedef float f32x4 __attribute__((ext_vector_type(4)));

typedef unsigned int u32_t;
typedef __attribute__((address_space(1))) const u32_t gu32_t;
typedef __attribute__((address_space(3))) u32_t lu32_t;

// async global->LDS, 16B per lane, wave-uniform LDS base + lane*16
__device__ __forceinline__ void gload16(const __bf16* g, __bf16* l){
    __builtin_amdgcn_global_load_lds((gu32_t*)g, (lu32_t*)l, 16, 0, 0);
}

// ---------------- block reduction ----------------
__device__ __forceinline__ float block_reduce_sum(float v){
    __shared__ float sm[8];
    #pragma unroll
    for (int off = 32; off > 0; off >>= 1) v += __shfl_xor(v, off);
    int lane = threadIdx.x & 63, wid = threadIdx.x >> 6;
    if (lane == 0) sm[wid] = v;
    __syncthreads();
    if (threadIdx.x == 0){
        float t = 0.f;
        int nw = blockDim.x >> 6;
        for (int i = 0; i < nw; i++) t += sm[i];
        sm[0] = t;
    }
    __syncthreads();
    return sm[0];
}

// ---------------- copy x -> X ----------------
__global__ void copy_kernel(const float* __restrict__ x, float* __restrict__ X, int n){
    int i = blockIdx.x * blockDim.x + threadIdx.x;
    if (i < n) X[i] = x[i];
}

// ---------------- per-row inverse-RMS of X[ROWS][512] ----------------
__global__ __launch_bounds__(64) void rowscale_kernel(const float* __restrict__ X,
                                                      float* __restrict__ rs){
    int row = blockIdx.x, lane = threadIdx.x;
    const float* xr = X + (size_t)row * DM_;
    float ss = 0.f;
    #pragma unroll
    for (int i = 0; i < DM_ / 64; i++){ float v = xr[lane + 64 * i]; ss += v * v; }
    #pragma unroll
    for (int off = 32; off > 0; off >>= 1) ss += __shfl_xor(ss, off);
    if (lane == 0) rs[row] = rsqrtf(ss / (float)DM_ + EPS_);
}

// ---------------- final rmsnorm -> f32 out ----------------
__global__ void finalnorm_kernel(const float* __restrict__ in, const float* __restrict__ w,
                                 float* __restrict__ out){
    int row = blockIdx.x;
    const float* xr = in + (size_t)row * DM_;
    float ss = 0.f;
    for (int c = threadIdx.x; c < DM_; c += blockDim.x){ float v = xr[c]; ss += v * v; }
    float tot = block_reduce_sum(ss);
    float rsv = rsqrtf(tot / (float)DM_ + EPS_);
    float* orow = out + (size_t)row * DM_;
    for (int c = threadIdx.x; c < DM_; c += blockDim.x)
        orow[c] = xr[c] * rsv * w[c];
}

// ---------------- split-convert A: X(f32,lda) [*rs[m]] [*wv[k]] -> A2[M][2K] bf16 (hi|lo) ----------------
__global__ void convA_kernel(const float* __restrict__ X, int lda,
                             const float* __restrict__ rs, const float* __restrict__ wv,
                             __bf16* __restrict__ A2, int M, int K){
    int idx = blockIdx.x * blockDim.x + threadIdx.x;
    if (idx >= M * K) return;
    int m = idx / K, k = idx - m * K;
    float a = X[(size_t)m * lda + k];
    if (rs) a *= rs[m];
    if (wv) a *= wv[k];
    __bf16 hi = (__bf16)a;
    A2[(size_t)m * (2 * K) + k] = hi;
    A2[(size_t)m * (2 * K) + K + k] = (__bf16)(a - (float)hi);
}

// ---------------- split-convert W: W(f32)[N][K] -> W2[Npad][2K] bf16 (hi|lo), zero pad rows ----------------
__global__ void convW_kernel(const float* __restrict__ W, __bf16* __restrict__ W2,
                             int N, int Npad, int K){
    int idx = blockIdx.x * blockDim.x + threadIdx.x;
    if (idx >= Npad * K) return;
    int n = idx / K, k = idx - n * K;
    size_t ro = (size_t)n * (2 * K);
    if (n >= N){
        W2[ro + k] = (__bf16)0.f; W2[ro + K + k] = (__bf16)0.f;
        return;
    }
    float w = W[(size_t)n * K + k];
    __bf16 hi = (__bf16)w;
    __bf16 lo = (__bf16)(w - (float)hi);
    W2[ro + k] = hi; W2[ro + K + k] = lo;
}

// ---------------- split-K reduce: X += bias + P[0] + P[1] (N=512 rows) ----------------
__global__ void reduceK_kernel(const float* __restrict__ P, const float* __restrict__ bias,
                               float* __restrict__ X, int MN){
    int i = blockIdx.x * blockDim.x + threadIdx.x;        // float4 index
    if (i * 4 >= MN) return;
    float4 a = reinterpret_cast<const float4*>(P)[i];
    float4 b = reinterpret_cast<const float4*>(P + MN)[i];
    float4 x = reinterpret_cast<const float4*>(X)[i];
    float4 r;
    r.x = x.x + a.x + b.x; r.y = x.y + a.y + b.y;
    r.z = x.z + a.z + b.z; r.w = x.w + a.w + b.w;
    if (bias){
        int n = (i * 4) & (DM_ - 1);
        r.x += bias[n]; r.y += bias[n + 1]; r.z += bias[n + 2]; r.w += bias[n + 3];
    }
    reinterpret_cast<float4*>(X)[i] = r;
}

// ---------------- split-bf16 MFMA GEMM: C = A2 x W2^T, hi/lo-chunk K-loop ----------------
// A2[M][2K] (hi|lo), W2[Npad][2K] (hi|lo). Per physical 32-col chunk: stage
// A_hi,A_lo,W_hi,W_lo then acc += Ah*Wh + Ah*Wl + Al*Wh (3x MFMA per staged chunk:
// 33% less staging traffic + 3x fewer barriers than 3-pass format).
// 4 waves, wave tile BM/2 x BN/2, triple-buffered LDS, 2-deep prefetch, counted vmcnt,
// setprio on MFMA cluster; R5-verified swizzle (q = s^((r>>1)&3); read seg quad^((lm>>1)&3)).
// XCD-aware 1-D grid: xcd = bid&7 selects n-tile group (W-slice L2-resident per XCD),
// m streams within XCD; ghost blocks (n_tile >= NTN) exit. Split-K via gridDim.z.
template<int BM, int BN>
__global__ __launch_bounds__(256, (BM == 64) ? 3 : 2) void gemm_mfma_kernel(
    const __bf16* __restrict__ A2, const __bf16* __restrict__ W2,
    const float* __restrict__ bias, const float* __restrict__ resid, int ldr,
    float* __restrict__ Pf,
    float* __restrict__ Cf, int ldc, __bf16* __restrict__ Cs, int csK,
    int M, int N, int K, int act, int NTM, int NTN)
{
    constexpr int WTM = BM / 2, WTN = BN / 2;
    constexpr int NI  = WTM / 16;         // M frags per wave
    constexpr int NJ  = WTN / 16;         // N frags per wave
    constexpr int NLD = (BM + BN) / 32;   // gload16 per wave per stage
    constexpr int AH  = BM * 32;          // elems per A hi tile
    constexpr int WH  = BN * 32;
    __shared__ __attribute__((aligned(16))) __bf16 As[3][2 * AH];   // [hi|lo]
    __shared__ __attribute__((aligned(16))) __bf16 Ws[3][2 * WH];
    int bid = blockIdx.x;
    int xcd = bid & 7, li = bid >> 3;
    int mt = li % NTM, g = li / NTM;
    int ntile = g * 8 + xcd;
    if (ntile >= NTN) return;             // ghost block
    int m0 = mt * BM, n0 = ntile * BN;
    int tid = threadIdx.x;
    int wv = tid >> 6, lane = tid & 63;
    int wm = (wv >> 1) * WTM;
    int wn = (wv & 1) * WTN;
    int lm = lane & 15, quad = lane >> 4;
    int soff = ((quad ^ ((lm >> 1) & 3)) * 8);   // swizzled read segment (per-lane const)
    const int ldA = 2 * K, ldW = 2 * K;
    const int nchunk = K / 32;
    const int ntl = nchunk / gridDim.z;
    const int tb = blockIdx.z * ntl;

    f32x4 acc[NI][NJ] = {};

    // stage physical chunk t (cols t*32..t*32+31, hi and lo) into buffer buf
    auto stage = [&](int buf, int t){
        int kc = t * 32;
        #pragma unroll
        for (int u = 0; u < BM / 64; u++){
            int cb = (wv * (BM / 64) + u) * 64;
            int c = cb + lane;
            int r = c >> 2, s = c & 3, q = s ^ ((r >> 1) & 3);
            const __bf16* ga = A2 + (size_t)(m0 + r) * ldA + kc + q * 8;
            gload16(ga,     &As[buf][cb * 8]);
            gload16(ga + K, &As[buf][AH + cb * 8]);
        }
        #pragma unroll
        for (int u = 0; u < BN / 64; u++){
            int cb = (wv * (BN / 64) + u) * 64;
            int c = cb + lane;
            int r = c >> 2, s = c & 3, q = s ^ ((r >> 1) & 3);
            const __bf16* gw = W2 + (size_t)(n0 + r) * ldW + kc + q * 8;
            gload16(gw,     &Ws[buf][cb * 8]);
            gload16(gw + K, &Ws[buf][WH + cb * 8]);
        }
    };

    stage(0, tb);
    stage(1, tb + 1);
    if constexpr (NLD == 6) asm volatile("s_waitcnt vmcnt(6)" ::: "memory");
    else                    asm volatile("s_waitcnt vmcnt(4)" ::: "memory");
    __builtin_amdgcn_s_barrier();

    int cur = 0;
    for (int tt = 0; tt < ntl; tt++){
        bool staged = (tt + 2 < ntl);
        if (staged){
            int nb = cur + 2; if (nb >= 3) nb -= 3;
            stage(nb, tb + tt + 2);
        }

        bfx8 ah[NI], al[NI], bh[NJ], bl[NJ];
        #pragma unroll
        for (int i = 0; i < NI; i++){
            int ra = (wm + i * 16 + lm) * 32 + soff;
            ah[i] = *reinterpret_cast<const bfx8*>(&As[cur][ra]);
            al[i] = *reinterpret_cast<const bfx8*>(&As[cur][AH + ra]);
        }
        #pragma unroll
        for (int j = 0; j < NJ; j++){
            int rb = (wn + j * 16 + lm) * 32 + soff;
            bh[j] = *reinterpret_cast<const bfx8*>(&Ws[cur][rb]);
            bl[j] = *reinterpret_cast<const bfx8*>(&Ws[cur][WH + rb]);
        }

        __builtin_amdgcn_s_setprio(1);
        #pragma unroll
        for (int i = 0; i < NI; i++)
            #pragma unroll
            for (int j = 0; j < NJ; j++)
                acc[i][j] = __builtin_amdgcn_mfma_f32_16x16x32_bf16(
                    ah[i], bh[j], acc[i][j], 0, 0, 0);
        #pragma unroll
        for (int i = 0; i < NI; i++)
            #pragma unroll
            for (int j = 0; j < NJ; j++)
                acc[i][j] = __builtin_amdgcn_mfma_f32_16x16x32_bf16(
                    ah[i], bl[j], acc[i][j], 0, 0, 0);
        #pragma unroll
        for (int i = 0; i < NI; i++)
            #pragma unroll
            for (int j = 0; j < NJ; j++)
                acc[i][j] = __builtin_amdgcn_mfma_f32_16x16x32_bf16(
                    al[i], bh[j], acc[i][j], 0, 0, 0);
        __builtin_amdgcn_s_setprio(0);

        if (staged){
            if constexpr (NLD == 6) asm volatile("s_waitcnt vmcnt(6)" ::: "memory");
            else                    asm volatile("s_waitcnt vmcnt(4)" ::: "memory");
        } else {
            asm volatile("s_waitcnt vmcnt(0)" ::: "memory");
        }
        __builtin_amdgcn_s_barrier();
        cur = cur + 1; if (cur >= 3) cur = 0;
    }

    if (Pf){
        float* pc = Pf + (size_t)blockIdx.z * M * N;
        #pragma unroll
        for (int i = 0; i < NI; i++)
            #pragma unroll
            for (int j = 0; j < NJ; j++){
                int n = n0 + wn + j * 16 + lm;
                #pragma unroll
                for (int r = 0; r < 4; r++){
                    int m = m0 + wm + i * 16 + quad * 4 + r;
                    pc[(size_t)m * N + n] = acc[i][j][r];
                }
            }
        return;
    }

    #pragma unroll
    for (int i = 0; i < NI; i++){
        #pragma unroll
        for (int j = 0; j < NJ; j++){
            int n = n0 + wn + j * 16 + lm;
            if (n < N){
                #pragma unroll
                for (int r = 0; r < 4; r++){
                    int m = m0 + wm + i * 16 + quad * 4 + r;
                    float c = acc[i][j][r];
                    if (bias) c += bias[n];
                    if (act == 1) c = 0.5f * c * (1.f + erff(c * 0.70710678118654752f));
                    if (resid) c += resid[(size_t)m * ldr + n];
                    if (Cf) Cf[(size_t)m * ldc + n] = c;
                    else {
                        __bf16 hi = (__bf16)c;
                        Cs[(size_t)m * (2 * csK) + n] = hi;
                        Cs[(size_t)m * (2 * csK) + csK + n] = (__bf16)(c - (float)hi);
                    }
                }
            }
        }
    }
}

// ---------------- conv+silu for the 32 B/C channels -> BCc[ROWS][32] ----------------
__global__ void bcconv_kernel(const float* __restrict__ ZX, const float* __restrict__ cw,
                              const float* __restrict__ cb, float* __restrict__ BCc){
    int idx = blockIdx.x * blockDim.x + threadIdx.x;
    if (idx >= ROWS_ * 32) return;
    int j = idx & 31;
    int row = idx >> 5;
    int l = row & (L_ - 1);
    float acc = cb[DI_ + j];
    #pragma unroll
    for (int k = 0; k < 4; k++){
        int lt = l + k - 3;
        if (lt >= 0)
            acc += ZX[(size_t)(row + k - 3) * DPROJ_ + (DI_ + DI_) + j] * cw[(DI_ + j) * 4 + k];
    }
    BCc[idx] = acc / (1.f + expf(-acc));
}

// ---------------- dt = softplus(raw + dt_bias); dA = exp(-exp(A_log)*dt) ----------------
__global__ void dt_kernel(const float* __restrict__ ZX, const float* __restrict__ dtb,
                          const float* __restrict__ Alog, float* __restrict__ DT,
                          float* __restrict__ DA){
    int idx = blockIdx.x * blockDim.x + threadIdx.x;
    if (idx >= ROWS_ * NH_) return;
    int h = idx & 15; int row = idx >> 4;
    float v = ZX[(size_t)row * DPROJ_ + (DPROJ_ - NH_) + h] + dtb[h];
    float dtv = (v > 20.f) ? v : log1pf(expf(v));
    DT[idx] = dtv;
    DA[idx] = expf(-expf(Alog[h]) * dtv);
}

// ======== chunked SSM scan (3 phases); blk = b*(NH*NCHUNK)+h*NCHUNK+c ; lane = p ========
__global__ __launch_bounds__(64) void scanA_kernel(const float* __restrict__ ZX,
                                                   const float* __restrict__ BCc,
                                                   const float* __restrict__ DT,
                                                   const float* __restrict__ DA,
                                                   const float* __restrict__ cw,
                                                   const float* __restrict__ cb,
                                                   float* __restrict__ SCH,
                                                   float* __restrict__ PCH,
                                                   float* __restrict__ XWIN){
    int blk = blockIdx.x;
    int c = blk & (NCHUNK_ - 1); int h = (blk >> 4) & (NH_ - 1); int b = blk >> 8;
    int p = threadIdx.x;
    int ch = h * HD_ + p;
    float cw0 = cw[ch * 4 + 0], cw1 = cw[ch * 4 + 1], cw2 = cw[ch * 4 + 2], cw3 = cw[ch * 4 + 3];
    float cbc = cb[ch];
    size_t colx = (size_t)DI_ + ch;
    int t0 = c * CLEN_;
    float w0 = 0.f, w1 = 0.f, w2 = 0.f;
    if (c > 0){
        w0 = ZX[(size_t)(b * L_ + t0 - 3) * DPROJ_ + colx];
        w1 = ZX[(size_t)(b * L_ + t0 - 2) * DPROJ_ + colx];
        w2 = ZX[(size_t)(b * L_ + t0 - 1) * DPROJ_ + colx];
    }
    float* xw = XWIN + (size_t)blk * (3 * 64);
    xw[0 * 64 + p] = w0; xw[1 * 64 + p] = w1; xw[2 * 64 + p] = w2;

    float s[16];
    #pragma unroll
    for (int n = 0; n < 16; n++) s[n] = 0.f;
    float pprod = 1.f;

    for (int tt = 0; tt < CLEN_; tt++){
        int row = b * L_ + t0 + tt;
        size_t rowoff = (size_t)row * DPROJ_;
        float cur = ZX[rowoff + colx];
        float pre = cbc + cw0 * w0 + cw1 * w1 + cw2 * w2 + cw3 * cur;
        float xc = pre / (1.f + expf(-pre));
        w0 = w1; w1 = w2; w2 = cur;
        float dtv = DT[row * NH_ + h];
        float dav = DA[row * NH_ + h];
        pprod *= dav;
        float bc[16];
        const float4* bp = reinterpret_cast<const float4*>(BCc + (size_t)row * 32);
        #pragma unroll
        for (int i = 0; i < 4; i++){
            float4 v = bp[i];
            bc[4 * i + 0] = v.x; bc[4 * i + 1] = v.y; bc[4 * i + 2] = v.z; bc[4 * i + 3] = v.w;
        }
        float coef = dtv * xc;
        #pragma unroll
        for (int n = 0; n < 16; n++)
            s[n] = fmaf(s[n], dav, coef * bc[n]);
    }
    float* sc = SCH + (size_t)blk * 1024 + p * 16;
    #pragma unroll
    for (int i = 0; i < 4; i++)
        *reinterpret_cast<float4*>(sc + 4 * i) = make_float4(s[4*i], s[4*i+1], s[4*i+2], s[4*i+3]);
    if (p == 0) PCH[blk] = pprod;
}

__global__ __launch_bounds__(64) void scanB_kernel(float* __restrict__ SCH,
                                                   const float* __restrict__ PCH){
    int bh = blockIdx.x;
    int p = threadIdx.x;
    float s[16];
    #pragma unroll
    for (int n = 0; n < 16; n++) s[n] = 0.f;
    for (int c = 0; c < NCHUNK_; c++){
        int blk = bh * NCHUNK_ + c;
        float* sc = SCH + (size_t)blk * 1024 + p * 16;
        float loc[16];
        #pragma unroll
        for (int i = 0; i < 4; i++){
            float4 v = *reinterpret_cast<const float4*>(sc + 4 * i);
            loc[4*i] = v.x; loc[4*i+1] = v.y; loc[4*i+2] = v.z; loc[4*i+3] = v.w;
        }
        float P = PCH[blk];
        #pragma unroll
        for (int i = 0; i < 4; i++)
            *reinterpret_cast<float4*>(sc + 4 * i) = make_float4(s[4*i], s[4*i+1], s[4*i+2], s[4*i+3]);
        #pragma unroll
        for (int n = 0; n < 16; n++)
            s[n] = fmaf(P, s[n], loc[n]);
    }
}

__global__ __launch_bounds__(64) void scanC_kernel(float* __restrict__ ZX,
                                                   const float* __restrict__ BCc,
                                                   const float* __restrict__ DT,
                                                   const float* __restrict__ DA,
                                                   const float* __restrict__ cw,
                                                   const float* __restrict__ cb,
                                                   const float* __restrict__ Dh,
                                                   const float* __restrict__ SCH,
                                                   const float* __restrict__ XWIN){
    int blk = blockIdx.x;
    int c = blk & (NCHUNK_ - 1); int h = (blk >> 4) & (NH_ - 1); int b = blk >> 8;
    int p = threadIdx.x;
    int ch = h * HD_ + p;
    float cw0 = cw[ch * 4 + 0], cw1 = cw[ch * 4 + 1], cw2 = cw[ch * 4 + 2], cw3 = cw[ch * 4 + 3];
    float cbc = cb[ch];
    float Dv = Dh[h];
    size_t colx = (size_t)DI_ + ch;
    int t0 = c * CLEN_;
    const float* xw = XWIN + (size_t)blk * (3 * 64);
    float w0 = xw[0 * 64 + p], w1 = xw[1 * 64 + p], w2 = xw[2 * 64 + p];
    const float* sc = SCH + (size_t)blk * 1024 + p * 16;
    float s[16];
    #pragma unroll
    for (int i = 0; i < 4; i++){
        float4 v = *reinterpret_cast<const float4*>(sc + 4 * i);
        s[4*i] = v.x; s[4*i+1] = v.y; s[4*i+2] = v.z; s[4*i+3] = v.w;
    }

    for (int tt = 0; tt < CLEN_; tt++){
        int row = b * L_ + t0 + tt;
        size_t rowoff = (size_t)row * DPROJ_;
        float cur = ZX[rowoff + colx];
        float pre = cbc + cw0 * w0 + cw1 * w1 + cw2 * w2 + cw3 * cur;
        float xc = pre / (1.f + expf(-pre));
        w0 = w1; w1 = w2; w2 = cur;
        float dtv = DT[row * NH_ + h];
        float dav = DA[row * NH_ + h];
        float bc[32];
        const float4* bp = reinterpret_cast<const float4*>(BCc + (size_t)row * 32);
        #pragma unroll
        for (int i = 0; i < 8; i++){
            float4 v = bp[i];
            bc[4 * i + 0] = v.x; bc[4 * i + 1] = v.y; bc[4 * i + 2] = v.z; bc[4 * i + 3] = v.w;
        }
        float coef = dtv * xc;
        float y = 0.f;
        #pragma unroll
        for (int n = 0; n < 16; n++){
            s[n] = fmaf(s[n], dav, coef * bc[n]);
            y += s[n] * bc[16 + n];
        }
        ZX[rowoff + colx] = fmaf(Dv, xc, y);
    }
}

// ---------------- gated rmsnorm in place on ZX ----------------
__global__ void gatenorm_kernel(float* __restrict__ ZX, const float* __restrict__ gw){
    int row = blockIdx.x;
    float* zr = ZX + (size_t)row * DPROJ_;
    float* yr = zr + DI_;
    float ss = 0.f;
    for (int cc = threadIdx.x; cc < DI_; cc += blockDim.x){
        float z = zr[cc];
        float v = yr[cc] * (z / (1.f + expf(-z)));
        yr[cc] = v;
        ss += v * v;
    }
    float tot = block_reduce_sum(ss);
    float rsv = rsqrtf(tot / (float)DI_ + EPS_);
    for (int cc = threadIdx.x; cc < DI_; cc += blockDim.x)
        yr[cc] = yr[cc] * rsv * gw[cc];
}

extern "C" void kernel_launch(void* const* d_in, const int* in_sizes, int n_in,
                              void* d_out, int out_size, void* d_ws, size_t ws_size,
                              hipStream_t stream){
    const float* x_in        = (const float*)d_in[0];
    const float* in_proj_w   = (const float*)d_in[1];
    const float* conv_w      = (const float*)d_in[2];
    const float* conv_b      = (const float*)d_in[3];
    const float* dt_bias     = (const float*)d_in[4];
    const float* A_log       = (const float*)d_in[5];
    const float* D_ssm       = (const float*)d_in[6];
    const float* gnorm_w     = (const float*)d_in[7];
    const float* out_proj_w  = (const float*)d_in[8];
    const float* ffn_w1      = (const float*)d_in[9];
    const float* ffn_b1      = (const float*)d_in[10];
    const float* ffn_w2      = (const float*)d_in[11];
    const float* ffn_b2      = (const float*)d_in[12];
    const float* norm_mamba_w= (const float*)d_in[13];
    const float* norm_ffn_w  = (const float*)d_in[14];
    const float* final_norm_w= (const float*)d_in[15];

    // ---- workspace layout (same offsets as R5; W2 now uses less of its region) ----
    float* X    = (float*)d_ws;                       // 2,097,152 f
    float* RS   = X    + 2097152;                     // 4096
    float* BCc  = RS   + 4096;                        // 131072
    float* DT   = BCc  + 131072;                      // 65536
    float* DA   = DT   + 65536;                       // 65536
    float* SCH  = DA   + 65536;                       // 1,048,576
    float* PCH  = SCH  + 1048576;                     // 1024
    float* XWIN = PCH  + 1024;                        // 196,608
    __bf16* A2  = (__bf16*)(XWIN + 196608);           // 8,388,608 bf16 (max M x 2K, K=1024)
    __bf16* W2  = A2 + 8388608;                       // region 3,342,336 bf16 (used: <=2176x2K)
    float* ZX   = (float*)(W2 + 3342336);             // 4096 x 2096 f32 (also H-split region)
    __bf16* Hs  = (__bf16*)ZX;                        // 4096 x 4096 bf16 (ffn hidden, hi|lo)
    // split-K partial buffers (aliased, each 2 x 4096 x 512 f32 = 16 MiB):
    float* PART_OP = ZX;                              // out_proj: ZX dead after convA
    float* PART_F2 = (float*)A2;                      // ffn2: A2 unused (A = Hs)

    const int NBLK = B_ * NH_ * NCHUNK_;              // 1024

    copy_kernel<<<(ROWS_ * DM_ + 255) / 256, 256, 0, stream>>>(x_in, X, ROWS_ * DM_);

    for (int l = 0; l < NLAYERS; l++){
        const float* cwl = conv_w + (size_t)l * CONVD_ * 4;
        const float* cbl = conv_b + (size_t)l * CONVD_;

        // ---- mamba: fused rmsnorm into A-conversion, then MFMA in_proj ----
        rowscale_kernel<<<ROWS_, 64, 0, stream>>>(X, RS);
        convA_kernel<<<(ROWS_ * DM_ + 255) / 256, 256, 0, stream>>>(
            X, DM_, RS, norm_mamba_w + (size_t)l * DM_, A2, ROWS_, DM_);
        convW_kernel<<<(2176 * DM_ + 255) / 256, 256, 0, stream>>>(
            in_proj_w + (size_t)l * DPROJ_ * DM_, W2, DPROJ_, 2176, DM_);
        {
            // NTM=32 (BM=128), NTN=34 (BN=64), NTG=5 -> grid 32*5*8 = 1280 (ghosts exit)
            gemm_mfma_kernel<128,64><<<dim3(1280,1,1), 256, 0, stream>>>(
                A2, W2, nullptr, nullptr, 0, nullptr,
                ZX, DPROJ_, nullptr, 0, ROWS_, DPROJ_, DM_, 0, 32, 34);
        }

        bcconv_kernel<<<(ROWS_ * 32 + 255) / 256, 256, 0, stream>>>(ZX, cwl, cbl, BCc);
        dt_kernel<<<(ROWS_ * NH_ + 255) / 256, 256, 0, stream>>>(
            ZX, dt_bias + (size_t)l * NH_, A_log + (size_t)l * NH_, DT, DA);

        scanA_kernel<<<NBLK, 64, 0, stream>>>(ZX, BCc, DT, DA, cwl, cbl, SCH, PCH, XWIN);
        scanB_kernel<<<B_ * NH_, 64, 0, stream>>>(SCH, PCH);
        scanC_kernel<<<NBLK, 64, 0, stream>>>(ZX, BCc, DT, DA, cwl, cbl,
                                              D_ssm + (size_t)l * NH_, SCH, XWIN);

        gatenorm_kernel<<<ROWS_, 256, 0, stream>>>(ZX, gnorm_w + (size_t)l * DI_);

        // ---- out_proj (split-K x2 -> partials in ZX region -> reduce into X) ----
        convA_kernel<<<(ROWS_ * DI_ + 255) / 256, 256, 0, stream>>>(
            ZX + DI_, DPROJ_, nullptr, nullptr, A2, ROWS_, DI_);
        convW_kernel<<<(DM_ * DI_ + 255) / 256, 256, 0, stream>>>(
            out_proj_w + (size_t)l * DM_ * DI_, W2, DM_, DM_, DI_);
        {
            // NTM=64, NTN=8 -> grid 512 x z2
            gemm_mfma_kernel<64,64><<<dim3(512,1,2), 256, 0, stream>>>(
                A2, W2, nullptr, nullptr, 0, PART_OP,
                nullptr, 0, nullptr, 0, ROWS_, DM_, DI_, 0, 64, 8);
        }
        reduceK_kernel<<<(ROWS_ * DM_ / 4 + 255) / 256, 256, 0, stream>>>(
            PART_OP, nullptr, X, ROWS_ * DM_);

        // ---- ffn: norm->conv, ffn1 emits bf16 split hidden, ffn2 split-K + reduce ----
        rowscale_kernel<<<ROWS_, 64, 0, stream>>>(X, RS);
        convA_kernel<<<(ROWS_ * DM_ + 255) / 256, 256, 0, stream>>>(
            X, DM_, RS, norm_ffn_w + (size_t)l * DM_, A2, ROWS_, DM_);
        convW_kernel<<<(DFF_ * DM_ + 255) / 256, 256, 0, stream>>>(
            ffn_w1 + (size_t)l * DFF_ * DM_, W2, DFF_, DFF_, DM_);
        {
            // NTM=32, NTN=32, NTG=4 -> grid 1024
            gemm_mfma_kernel<128,64><<<dim3(1024,1,1), 256, 0, stream>>>(
                A2, W2, ffn_b1 + (size_t)l * DFF_, nullptr, 0, nullptr,
                nullptr, 0, Hs, DFF_, ROWS_, DFF_, DM_, 1, 32, 32);
        }
        convW_kernel<<<(DM_ * DFF_ + 255) / 256, 256, 0, stream>>>(
            ffn_w2 + (size_t)l * DM_ * DFF_, W2, DM_, DM_, DFF_);
        {
            gemm_mfma_kernel<64,64><<<dim3(512,1,2), 256, 0, stream>>>(
                Hs, W2, nullptr, nullptr, 0, PART_F2,
                nullptr, 0, nullptr, 0, ROWS_, DM_, DFF_, 0, 64, 8);
        }
        reduceK_kernel<<<(ROWS_ * DM_ / 4 + 255) / 256, 256, 0, stream>>>(
            PART_F2, ffn_b2 + (size_t)l * DM_, X, ROWS_ * DM_);
    }

    finalnorm_kernel<<<ROWS_, 256, 0, stream>>>(X, final_norm_w, (float*)d_out);
}

// Round 7
// 1985.521 us; speedup vs baseline: 1.0931x; 1.0931x over previous
//
#include <hip/hip_runtime.h>
#include <hip/hip_bf16.h>

#define NLAYERS 6
#define B_ 4
#define L_ 1024
#define DM_ 512
#define DI_ 1024
#define NH_ 16
#define HD_ 64
#define NS_ 16
#define CONVD_ 1056
#define DPROJ_ 2096
#define DFF_ 2048
#define ROWS_ (B_*L_)
#define EPS_ 1e-5f
#define NCHUNK_ 16
#define CLEN_ 64

typedef __bf16 bfx8 __attribute__((ext_vector_type(8)));
typedef float f32x4 __attribute__((ext_vector_type(4)));

typedef unsigned int u32_t;
typedef __attribute__((address_space(1))) const u32_t gu32_t;
typedef __attribute__((address_space(3))) u32_t lu32_t;

// async global->LDS, 16B per lane, wave-uniform LDS base + lane*16
__device__ __forceinline__ void gload16(const __bf16* g, __bf16* l){
    __builtin_amdgcn_global_load_lds((gu32_t*)g, (lu32_t*)l, 16, 0, 0);
}

// ---------------- block reduction ----------------
__device__ __forceinline__ float block_reduce_sum(float v){
    __shared__ float sm[8];
    #pragma unroll
    for (int off = 32; off > 0; off >>= 1) v += __shfl_xor(v, off);
    int lane = threadIdx.x & 63, wid = threadIdx.x >> 6;
    if (lane == 0) sm[wid] = v;
    __syncthreads();
    if (threadIdx.x == 0){
        float t = 0.f;
        int nw = blockDim.x >> 6;
        for (int i = 0; i < nw; i++) t += sm[i];
        sm[0] = t;
    }
    __syncthreads();
    return sm[0];
}

// ---------------- copy x -> X ----------------
__global__ void copy_kernel(const float* __restrict__ x, float* __restrict__ X, int n){
    int i = blockIdx.x * blockDim.x + threadIdx.x;
    if (i < n) X[i] = x[i];
}

// ---------------- final rmsnorm -> f32 out ----------------
__global__ void finalnorm_kernel(const float* __restrict__ in, const float* __restrict__ w,
                                 float* __restrict__ out){
    int row = blockIdx.x;
    const float* xr = in + (size_t)row * DM_;
    float ss = 0.f;
    for (int c = threadIdx.x; c < DM_; c += blockDim.x){ float v = xr[c]; ss += v * v; }
    float tot = block_reduce_sum(ss);
    float rsv = rsqrtf(tot / (float)DM_ + EPS_);
    float* orow = out + (size_t)row * DM_;
    for (int c = threadIdx.x; c < DM_; c += blockDim.x)
        orow[c] = xr[c] * rsv * w[c];
}

// ---------------- fused rmsnorm + split-convert: X[row][512] -> A2[row][2*512] hi|lo ----------------
// One block (1 wave) per row: wave-reduce sum-of-squares, then scale by rsqrt * wv and convert.
// Same op order as the old rowscale+convA pair (ss/DM+eps -> rsqrt -> a*rs*wv).
__global__ __launch_bounds__(64) void convAN_kernel(const float* __restrict__ X,
                                                    const float* __restrict__ wv,
                                                    __bf16* __restrict__ A2){
    int row = blockIdx.x, lane = threadIdx.x;
    const float* xr = X + (size_t)row * DM_;
    float v[8];
    {
        float4 a = *reinterpret_cast<const float4*>(xr + lane * 8);
        float4 b = *reinterpret_cast<const float4*>(xr + lane * 8 + 4);
        v[0] = a.x; v[1] = a.y; v[2] = a.z; v[3] = a.w;
        v[4] = b.x; v[5] = b.y; v[6] = b.z; v[7] = b.w;
    }
    float ss = 0.f;
    #pragma unroll
    for (int i = 0; i < 8; i++) ss += v[i] * v[i];
    #pragma unroll
    for (int off = 32; off > 0; off >>= 1) ss += __shfl_xor(ss, off);
    float rsv = rsqrtf(ss / (float)DM_ + EPS_);
    __bf16* ar = A2 + (size_t)row * (2 * DM_);
    #pragma unroll
    for (int i = 0; i < 8; i++){
        float a = v[i] * rsv * wv[lane * 8 + i];
        __bf16 hi = (__bf16)a;
        ar[lane * 8 + i] = hi;
        ar[DM_ + lane * 8 + i] = (__bf16)(a - (float)hi);
    }
}

// ---------------- split-convert A: X(f32,lda) -> A2[M][2K] bf16 (hi|lo), no scaling ----------------
__global__ void convA_kernel(const float* __restrict__ X, int lda,
                             __bf16* __restrict__ A2, int M, int K){
    int idx = blockIdx.x * blockDim.x + threadIdx.x;
    if (idx >= M * K) return;
    int m = idx / K, k = idx - m * K;
    float a = X[(size_t)m * lda + k];
    __bf16 hi = (__bf16)a;
    A2[(size_t)m * (2 * K) + k] = hi;
    A2[(size_t)m * (2 * K) + K + k] = (__bf16)(a - (float)hi);
}

// ---------------- split-convert W: W(f32)[N][K] -> W2[Npad][2K] bf16 (hi|lo), zero pad rows ----------------
__global__ void convW_kernel(const float* __restrict__ W, __bf16* __restrict__ W2,
                             int N, int Npad, int K){
    int idx = blockIdx.x * blockDim.x + threadIdx.x;
    if (idx >= Npad * K) return;
    int n = idx / K, k = idx - n * K;
    size_t ro = (size_t)n * (2 * K);
    if (n >= N){
        W2[ro + k] = (__bf16)0.f; W2[ro + K + k] = (__bf16)0.f;
        return;
    }
    float w = W[(size_t)n * K + k];
    __bf16 hi = (__bf16)w;
    __bf16 lo = (__bf16)(w - (float)hi);
    W2[ro + k] = hi; W2[ro + K + k] = lo;
}

// ---------------- split-K reduce: X += bias + P[0] + P[1] (N=512 rows) ----------------
__global__ void reduceK_kernel(const float* __restrict__ P, const float* __restrict__ bias,
                               float* __restrict__ X, int MN){
    int i = blockIdx.x * blockDim.x + threadIdx.x;        // float4 index
    if (i * 4 >= MN) return;
    float4 a = reinterpret_cast<const float4*>(P)[i];
    float4 b = reinterpret_cast<const float4*>(P + MN)[i];
    float4 x = reinterpret_cast<const float4*>(X)[i];
    float4 r;
    r.x = x.x + a.x + b.x; r.y = x.y + a.y + b.y;
    r.z = x.z + a.z + b.z; r.w = x.w + a.w + b.w;
    if (bias){
        int n = (i * 4) & (DM_ - 1);
        r.x += bias[n]; r.y += bias[n + 1]; r.z += bias[n + 2]; r.w += bias[n + 3];
    }
    reinterpret_cast<float4*>(X)[i] = r;
}

// ---------------- split-bf16 MFMA GEMM: C = A2 x W2^T, hi/lo-chunk K-loop ----------------
// A2[M][2K] (hi|lo), W2[Npad][2K] (hi|lo). Per physical 32-col chunk: stage
// A_hi,A_lo,W_hi,W_lo then acc += Ah*Wh + Ah*Wl + Al*Wh (3 MFMA passes per staged chunk).
// 4 waves, wave tile BM/2 x BN/2, triple-buffered LDS, 2-deep prefetch, counted vmcnt,
// setprio on MFMA cluster; swizzle: source seg q = s^((r>>1)&3), read seg quad^((lm>>1)&3).
// Grid: 2-D (x = m-tile, y = n-tile) -- R5-proven A/W L3 sharing. Split-K via gridDim.z.
template<int BM, int BN>
__global__ __launch_bounds__(256, (BM == 64) ? 3 : 2) void gemm_mfma_kernel(
    const __bf16* __restrict__ A2, const __bf16* __restrict__ W2,
    const float* __restrict__ bias, const float* __restrict__ resid, int ldr,
    float* __restrict__ Pf,
    float* __restrict__ Cf, int ldc, __bf16* __restrict__ Cs, int csK,
    int M, int N, int K, int act)
{
    constexpr int WTM = BM / 2, WTN = BN / 2;
    constexpr int NI  = WTM / 16;         // M frags per wave
    constexpr int NJ  = WTN / 16;         // N frags per wave
    constexpr int NLD = (BM + BN) / 32;   // gload16 per wave per stage
    constexpr int AH  = BM * 32;          // elems per A hi tile
    constexpr int WH  = BN * 32;
    __shared__ __attribute__((aligned(16))) __bf16 As[3][2 * AH];   // [hi|lo]
    __shared__ __attribute__((aligned(16))) __bf16 Ws[3][2 * WH];
    int m0 = blockIdx.x * BM, n0 = blockIdx.y * BN;
    int tid = threadIdx.x;
    int wv = tid >> 6, lane = tid & 63;
    int wm = (wv >> 1) * WTM;
    int wn = (wv & 1) * WTN;
    int lm = lane & 15, quad = lane >> 4;
    int soff = ((quad ^ ((lm >> 1) & 3)) * 8);   // swizzled read segment (per-lane const)
    const int ldA = 2 * K, ldW = 2 * K;
    const int nchunk = K / 32;
    const int ntl = nchunk / gridDim.z;
    const int tb = blockIdx.z * ntl;

    f32x4 acc[NI][NJ] = {};

    // stage physical chunk t (cols t*32..t*32+31, hi and lo) into buffer buf
    auto stage = [&](int buf, int t){
        int kc = t * 32;
        #pragma unroll
        for (int u = 0; u < BM / 64; u++){
            int cb = (wv * (BM / 64) + u) * 64;
            int c = cb + lane;
            int r = c >> 2, s = c & 3, q = s ^ ((r >> 1) & 3);
            const __bf16* ga = A2 + (size_t)(m0 + r) * ldA + kc + q * 8;
            gload16(ga,     &As[buf][cb * 8]);
            gload16(ga + K, &As[buf][AH + cb * 8]);
        }
        #pragma unroll
        for (int u = 0; u < BN / 64; u++){
            int cb = (wv * (BN / 64) + u) * 64;
            int c = cb + lane;
            int r = c >> 2, s = c & 3, q = s ^ ((r >> 1) & 3);
            const __bf16* gw = W2 + (size_t)(n0 + r) * ldW + kc + q * 8;
            gload16(gw,     &Ws[buf][cb * 8]);
            gload16(gw + K, &Ws[buf][WH + cb * 8]);
        }
    };

    stage(0, tb);
    stage(1, tb + 1);
    if constexpr (NLD == 6) asm volatile("s_waitcnt vmcnt(6)" ::: "memory");
    else                    asm volatile("s_waitcnt vmcnt(4)" ::: "memory");
    __builtin_amdgcn_s_barrier();

    int cur = 0;
    for (int tt = 0; tt < ntl; tt++){
        bool staged = (tt + 2 < ntl);
        if (staged){
            int nb = cur + 2; if (nb >= 3) nb -= 3;
            stage(nb, tb + tt + 2);
        }

        bfx8 ah[NI], al[NI], bh[NJ], bl[NJ];
        #pragma unroll
        for (int i = 0; i < NI; i++){
            int ra = (wm + i * 16 + lm) * 32 + soff;
            ah[i] = *reinterpret_cast<const bfx8*>(&As[cur][ra]);
            al[i] = *reinterpret_cast<const bfx8*>(&As[cur][AH + ra]);
        }
        #pragma unroll
        for (int j = 0; j < NJ; j++){
            int rb = (wn + j * 16 + lm) * 32 + soff;
            bh[j] = *reinterpret_cast<const bfx8*>(&Ws[cur][rb]);
            bl[j] = *reinterpret_cast<const bfx8*>(&Ws[cur][WH + rb]);
        }

        __builtin_amdgcn_s_setprio(1);
        #pragma unroll
        for (int i = 0; i < NI; i++)
            #pragma unroll
            for (int j = 0; j < NJ; j++)
                acc[i][j] = __builtin_amdgcn_mfma_f32_16x16x32_bf16(
                    ah[i], bh[j], acc[i][j], 0, 0, 0);
        #pragma unroll
        for (int i = 0; i < NI; i++)
            #pragma unroll
            for (int j = 0; j < NJ; j++)
                acc[i][j] = __builtin_amdgcn_mfma_f32_16x16x32_bf16(
                    ah[i], bl[j], acc[i][j], 0, 0, 0);
        #pragma unroll
        for (int i = 0; i < NI; i++)
            #pragma unroll
            for (int j = 0; j < NJ; j++)
                acc[i][j] = __builtin_amdgcn_mfma_f32_16x16x32_bf16(
                    al[i], bh[j], acc[i][j], 0, 0, 0);
        __builtin_amdgcn_s_setprio(0);

        if (staged){
            if constexpr (NLD == 6) asm volatile("s_waitcnt vmcnt(6)" ::: "memory");
            else                    asm volatile("s_waitcnt vmcnt(4)" ::: "memory");
        } else {
            asm volatile("s_waitcnt vmcnt(0)" ::: "memory");
        }
        __builtin_amdgcn_s_barrier();
        cur = cur + 1; if (cur >= 3) cur = 0;
    }

    if (Pf){
        float* pc = Pf + (size_t)blockIdx.z * M * N;
        #pragma unroll
        for (int i = 0; i < NI; i++)
            #pragma unroll
            for (int j = 0; j < NJ; j++){
                int n = n0 + wn + j * 16 + lm;
                #pragma unroll
                for (int r = 0; r < 4; r++){
                    int m = m0 + wm + i * 16 + quad * 4 + r;
                    pc[(size_t)m * N + n] = acc[i][j][r];
                }
            }
        return;
    }

    #pragma unroll
    for (int i = 0; i < NI; i++){
        #pragma unroll
        for (int j = 0; j < NJ; j++){
            int n = n0 + wn + j * 16 + lm;
            if (n < N){
                #pragma unroll
                for (int r = 0; r < 4; r++){
                    int m = m0 + wm + i * 16 + quad * 4 + r;
                    float c = acc[i][j][r];
                    if (bias) c += bias[n];
                    if (act == 1) c = 0.5f * c * (1.f + erff(c * 0.70710678118654752f));
                    if (resid) c += resid[(size_t)m * ldr + n];
                    if (Cf) Cf[(size_t)m * ldc + n] = c;
                    else {
                        __bf16 hi = (__bf16)c;
                        Cs[(size_t)m * (2 * csK) + n] = hi;
                        Cs[(size_t)m * (2 * csK) + csK + n] = (__bf16)(c - (float)hi);
                    }
                }
            }
        }
    }
}

// ---------------- conv+silu for the 32 B/C channels -> BCc[ROWS][32] ----------------
__global__ void bcconv_kernel(const float* __restrict__ ZX, const float* __restrict__ cw,
                              const float* __restrict__ cb, float* __restrict__ BCc){
    int idx = blockIdx.x * blockDim.x + threadIdx.x;
    if (idx >= ROWS_ * 32) return;
    int j = idx & 31;
    int row = idx >> 5;
    int l = row & (L_ - 1);
    float acc = cb[DI_ + j];
    #pragma unroll
    for (int k = 0; k < 4; k++){
        int lt = l + k - 3;
        if (lt >= 0)
            acc += ZX[(size_t)(row + k - 3) * DPROJ_ + (DI_ + DI_) + j] * cw[(DI_ + j) * 4 + k];
    }
    BCc[idx] = acc / (1.f + expf(-acc));
}

// ---------------- dt = softplus(raw + dt_bias); dA = exp(-exp(A_log)*dt) ----------------
__global__ void dt_kernel(const float* __restrict__ ZX, const float* __restrict__ dtb,
                          const float* __restrict__ Alog, float* __restrict__ DT,
                          float* __restrict__ DA){
    int idx = blockIdx.x * blockDim.x + threadIdx.x;
    if (idx >= ROWS_ * NH_) return;
    int h = idx & 15; int row = idx >> 4;
    float v = ZX[(size_t)row * DPROJ_ + (DPROJ_ - NH_) + h] + dtb[h];
    float dtv = (v > 20.f) ? v : log1pf(expf(v));
    DT[idx] = dtv;
    DA[idx] = expf(-expf(Alog[h]) * dtv);
}

// ======== chunked SSM scan (3 phases); blk = b*(NH*NCHUNK)+h*NCHUNK+c ; lane = p ========
__global__ __launch_bounds__(64) void scanA_kernel(const float* __restrict__ ZX,
                                                   const float* __restrict__ BCc,
                                                   const float* __restrict__ DT,
                                                   const float* __restrict__ DA,
                                                   const float* __restrict__ cw,
                                                   const float* __restrict__ cb,
                                                   float* __restrict__ SCH,
                                                   float* __restrict__ PCH,
                                                   float* __restrict__ XWIN){
    int blk = blockIdx.x;
    int c = blk & (NCHUNK_ - 1); int h = (blk >> 4) & (NH_ - 1); int b = blk >> 8;
    int p = threadIdx.x;
    int ch = h * HD_ + p;
    float cw0 = cw[ch * 4 + 0], cw1 = cw[ch * 4 + 1], cw2 = cw[ch * 4 + 2], cw3 = cw[ch * 4 + 3];
    float cbc = cb[ch];
    size_t colx = (size_t)DI_ + ch;
    int t0 = c * CLEN_;
    float w0 = 0.f, w1 = 0.f, w2 = 0.f;
    if (c > 0){
        w0 = ZX[(size_t)(b * L_ + t0 - 3) * DPROJ_ + colx];
        w1 = ZX[(size_t)(b * L_ + t0 - 2) * DPROJ_ + colx];
        w2 = ZX[(size_t)(b * L_ + t0 - 1) * DPROJ_ + colx];
    }
    float* xw = XWIN + (size_t)blk * (3 * 64);
    xw[0 * 64 + p] = w0; xw[1 * 64 + p] = w1; xw[2 * 64 + p] = w2;

    float s[16];
    #pragma unroll
    for (int n = 0; n < 16; n++) s[n] = 0.f;
    float pprod = 1.f;

    for (int tt = 0; tt < CLEN_; tt++){
        int row = b * L_ + t0 + tt;
        size_t rowoff = (size_t)row * DPROJ_;
        float cur = ZX[rowoff + colx];
        float pre = cbc + cw0 * w0 + cw1 * w1 + cw2 * w2 + cw3 * cur;
        float xc = pre / (1.f + expf(-pre));
        w0 = w1; w1 = w2; w2 = cur;
        float dtv = DT[row * NH_ + h];
        float dav = DA[row * NH_ + h];
        pprod *= dav;
        float bc[16];
        const float4* bp = reinterpret_cast<const float4*>(BCc + (size_t)row * 32);
        #pragma unroll
        for (int i = 0; i < 4; i++){
            float4 v = bp[i];
            bc[4 * i + 0] = v.x; bc[4 * i + 1] = v.y; bc[4 * i + 2] = v.z; bc[4 * i + 3] = v.w;
        }
        float coef = dtv * xc;
        #pragma unroll
        for (int n = 0; n < 16; n++)
            s[n] = fmaf(s[n], dav, coef * bc[n]);
    }
    float* sc = SCH + (size_t)blk * 1024 + p * 16;
    #pragma unroll
    for (int i = 0; i < 4; i++)
        *reinterpret_cast<float4*>(sc + 4 * i) = make_float4(s[4*i], s[4*i+1], s[4*i+2], s[4*i+3]);
    if (p == 0) PCH[blk] = pprod;
}

__global__ __launch_bounds__(64) void scanB_kernel(float* __restrict__ SCH,
                                                   const float* __restrict__ PCH){
    int bh = blockIdx.x;
    int p = threadIdx.x;
    float s[16];
    #pragma unroll
    for (int n = 0; n < 16; n++) s[n] = 0.f;
    for (int c = 0; c < NCHUNK_; c++){
        int blk = bh * NCHUNK_ + c;
        float* sc = SCH + (size_t)blk * 1024 + p * 16;
        float loc[16];
        #pragma unroll
        for (int i = 0; i < 4; i++){
            float4 v = *reinterpret_cast<const float4*>(sc + 4 * i);
            loc[4*i] = v.x; loc[4*i+1] = v.y; loc[4*i+2] = v.z; loc[4*i+3] = v.w;
        }
        float P = PCH[blk];
        #pragma unroll
        for (int i = 0; i < 4; i++)
            *reinterpret_cast<float4*>(sc + 4 * i) = make_float4(s[4*i], s[4*i+1], s[4*i+2], s[4*i+3]);
        #pragma unroll
        for (int n = 0; n < 16; n++)
            s[n] = fmaf(P, s[n], loc[n]);
    }
}

__global__ __launch_bounds__(64) void scanC_kernel(float* __restrict__ ZX,
                                                   const float* __restrict__ BCc,
                                                   const float* __restrict__ DT,
                                                   const float* __restrict__ DA,
                                                   const float* __restrict__ cw,
                                                   const float* __restrict__ cb,
                                                   const float* __restrict__ Dh,
                                                   const float* __restrict__ SCH,
                                                   const float* __restrict__ XWIN){
    int blk = blockIdx.x;
    int c = blk & (NCHUNK_ - 1); int h = (blk >> 4) & (NH_ - 1); int b = blk >> 8;
    int p = threadIdx.x;
    int ch = h * HD_ + p;
    float cw0 = cw[ch * 4 + 0], cw1 = cw[ch * 4 + 1], cw2 = cw[ch * 4 + 2], cw3 = cw[ch * 4 + 3];
    float cbc = cb[ch];
    float Dv = Dh[h];
    size_t colx = (size_t)DI_ + ch;
    int t0 = c * CLEN_;
    const float* xw = XWIN + (size_t)blk * (3 * 64);
    float w0 = xw[0 * 64 + p], w1 = xw[1 * 64 + p], w2 = xw[2 * 64 + p];
    const float* sc = SCH + (size_t)blk * 1024 + p * 16;
    float s[16];
    #pragma unroll
    for (int i = 0; i < 4; i++){
        float4 v = *reinterpret_cast<const float4*>(sc + 4 * i);
        s[4*i] = v.x; s[4*i+1] = v.y; s[4*i+2] = v.z; s[4*i+3] = v.w;
    }

    for (int tt = 0; tt < CLEN_; tt++){
        int row = b * L_ + t0 + tt;
        size_t rowoff = (size_t)row * DPROJ_;
        float cur = ZX[rowoff + colx];
        float pre = cbc + cw0 * w0 + cw1 * w1 + cw2 * w2 + cw3 * cur;
        float xc = pre / (1.f + expf(-pre));
        w0 = w1; w1 = w2; w2 = cur;
        float dtv = DT[row * NH_ + h];
        float dav = DA[row * NH_ + h];
        float bc[32];
        const float4* bp = reinterpret_cast<const float4*>(BCc + (size_t)row * 32);
        #pragma unroll
        for (int i = 0; i < 8; i++){
            float4 v = bp[i];
            bc[4 * i + 0] = v.x; bc[4 * i + 1] = v.y; bc[4 * i + 2] = v.z; bc[4 * i + 3] = v.w;
        }
        float coef = dtv * xc;
        float y = 0.f;
        #pragma unroll
        for (int n = 0; n < 16; n++){
            s[n] = fmaf(s[n], dav, coef * bc[n]);
            y += s[n] * bc[16 + n];
        }
        ZX[rowoff + colx] = fmaf(Dv, xc, y);
    }
}

// ---------------- gated rmsnorm in place on ZX ----------------
__global__ void gatenorm_kernel(float* __restrict__ ZX, const float* __restrict__ gw){
    int row = blockIdx.x;
    float* zr = ZX + (size_t)row * DPROJ_;
    float* yr = zr + DI_;
    float ss = 0.f;
    for (int cc = threadIdx.x; cc < DI_; cc += blockDim.x){
        float z = zr[cc];
        float v = yr[cc] * (z / (1.f + expf(-z)));
        yr[cc] = v;
        ss += v * v;
    }
    float tot = block_reduce_sum(ss);
    float rsv = rsqrtf(tot / (float)DI_ + EPS_);
    for (int cc = threadIdx.x; cc < DI_; cc += blockDim.x)
        yr[cc] = yr[cc] * rsv * gw[cc];
}

extern "C" void kernel_launch(void* const* d_in, const int* in_sizes, int n_in,
                              void* d_out, int out_size, void* d_ws, size_t ws_size,
                              hipStream_t stream){
    const float* x_in        = (const float*)d_in[0];
    const float* in_proj_w   = (const float*)d_in[1];
    const float* conv_w      = (const float*)d_in[2];
    const float* conv_b      = (const float*)d_in[3];
    const float* dt_bias     = (const float*)d_in[4];
    const float* A_log       = (const float*)d_in[5];
    const float* D_ssm       = (const float*)d_in[6];
    const float* gnorm_w     = (const float*)d_in[7];
    const float* out_proj_w  = (const float*)d_in[8];
    const float* ffn_w1      = (const float*)d_in[9];
    const float* ffn_b1      = (const float*)d_in[10];
    const float* ffn_w2      = (const float*)d_in[11];
    const float* ffn_b2      = (const float*)d_in[12];
    const float* norm_mamba_w= (const float*)d_in[13];
    const float* norm_ffn_w  = (const float*)d_in[14];
    const float* final_norm_w= (const float*)d_in[15];

    // ---- workspace layout (same offsets as R5/R6) ----
    float* X    = (float*)d_ws;                       // 2,097,152 f
    float* RS   = X    + 2097152;                     // 4096 (unused, kept for layout)
    float* BCc  = RS   + 4096;                        // 131072
    float* DT   = BCc  + 131072;                      // 65536
    float* DA   = DT   + 65536;                       // 65536
    float* SCH  = DA   + 65536;                       // 1,048,576
    float* PCH  = SCH  + 1048576;                     // 1024
    float* XWIN = PCH  + 1024;                        // 196,608
    __bf16* A2  = (__bf16*)(XWIN + 196608);           // 8,388,608 bf16 (max M x 2K, K=1024)
    __bf16* W2  = A2 + 8388608;                       // region 3,342,336 bf16 (used: <=2176x2K)
    float* ZX   = (float*)(W2 + 3342336);             // 4096 x 2096 f32 (also H-split region)
    __bf16* Hs  = (__bf16*)ZX;                        // 4096 x 4096 bf16 (ffn hidden, hi|lo)
    // split-K partial buffers (aliased, each 2 x 4096 x 512 f32 = 16 MiB):
    float* PART_OP = ZX;                              // out_proj: ZX dead after convA
    float* PART_F2 = (float*)A2;                      // ffn2: A2 unused (A = Hs)

    const int NBLK = B_ * NH_ * NCHUNK_;              // 1024

    copy_kernel<<<(ROWS_ * DM_ + 255) / 256, 256, 0, stream>>>(x_in, X, ROWS_ * DM_);

    for (int l = 0; l < NLAYERS; l++){
        const float* cwl = conv_w + (size_t)l * CONVD_ * 4;
        const float* cbl = conv_b + (size_t)l * CONVD_;

        // ---- mamba: fused rmsnorm+convert, then MFMA in_proj ----
        convAN_kernel<<<ROWS_, 64, 0, stream>>>(X, norm_mamba_w + (size_t)l * DM_, A2);
        convW_kernel<<<(2176 * DM_ + 255) / 256, 256, 0, stream>>>(
            in_proj_w + (size_t)l * DPROJ_ * DM_, W2, DPROJ_, 2176, DM_);
        {
            dim3 g(ROWS_ / 128, 2176 / 64, 1);
            gemm_mfma_kernel<128,64><<<g, 256, 0, stream>>>(
                A2, W2, nullptr, nullptr, 0, nullptr,
                ZX, DPROJ_, nullptr, 0, ROWS_, DPROJ_, DM_, 0);
        }

        bcconv_kernel<<<(ROWS_ * 32 + 255) / 256, 256, 0, stream>>>(ZX, cwl, cbl, BCc);
        dt_kernel<<<(ROWS_ * NH_ + 255) / 256, 256, 0, stream>>>(
            ZX, dt_bias + (size_t)l * NH_, A_log + (size_t)l * NH_, DT, DA);

        scanA_kernel<<<NBLK, 64, 0, stream>>>(ZX, BCc, DT, DA, cwl, cbl, SCH, PCH, XWIN);
        scanB_kernel<<<B_ * NH_, 64, 0, stream>>>(SCH, PCH);
        scanC_kernel<<<NBLK, 64, 0, stream>>>(ZX, BCc, DT, DA, cwl, cbl,
                                              D_ssm + (size_t)l * NH_, SCH, XWIN);

        gatenorm_kernel<<<ROWS_, 256, 0, stream>>>(ZX, gnorm_w + (size_t)l * DI_);

        // ---- out_proj (split-K x2 -> partials in ZX region -> reduce into X) ----
        convA_kernel<<<(ROWS_ * DI_ + 255) / 256, 256, 0, stream>>>(
            ZX + DI_, DPROJ_, A2, ROWS_, DI_);
        convW_kernel<<<(DM_ * DI_ + 255) / 256, 256, 0, stream>>>(
            out_proj_w + (size_t)l * DM_ * DI_, W2, DM_, DM_, DI_);
        {
            dim3 g(ROWS_ / 64, DM_ / 64, 2);
            gemm_mfma_kernel<64,64><<<g, 256, 0, stream>>>(
                A2, W2, nullptr, nullptr, 0, PART_OP,
                nullptr, 0, nullptr, 0, ROWS_, DM_, DI_, 0);
        }
        reduceK_kernel<<<(ROWS_ * DM_ / 4 + 255) / 256, 256, 0, stream>>>(
            PART_OP, nullptr, X, ROWS_ * DM_);

        // ---- ffn: fused norm+convert, ffn1 emits bf16 split hidden, ffn2 split-K + reduce ----
        convAN_kernel<<<ROWS_, 64, 0, stream>>>(X, norm_ffn_w + (size_t)l * DM_, A2);
        convW_kernel<<<(DFF_ * DM_ + 255) / 256, 256, 0, stream>>>(
            ffn_w1 + (size_t)l * DFF_ * DM_, W2, DFF_, DFF_, DM_);
        {
            dim3 g(ROWS_ / 128, DFF_ / 64, 1);
            gemm_mfma_kernel<128,64><<<g, 256, 0, stream>>>(
                A2, W2, ffn_b1 + (size_t)l * DFF_, nullptr, 0, nullptr,
                nullptr, 0, Hs, DFF_, ROWS_, DFF_, DM_, 1);
        }
        convW_kernel<<<(DM_ * DFF_ + 255) / 256, 256, 0, stream>>>(
            ffn_w2 + (size_t)l * DM_ * DFF_, W2, DM_, DM_, DFF_);
        {
            dim3 g(ROWS_ / 64, DM_ / 64, 2);
            gemm_mfma_kernel<64,64><<<g, 256, 0, stream>>>(
                Hs, W2, nullptr, nullptr, 0, PART_F2,
                nullptr, 0, nullptr, 0, ROWS_, DM_, DFF_, 0);
        }
        reduceK_kernel<<<(ROWS_ * DM_ / 4 + 255) / 256, 256, 0, stream>>>(
            PART_F2, ffn_b2 + (size_t)l * DM_, X, ROWS_ * DM_);
    }

    finalnorm_kernel<<<ROWS_, 256, 0, stream>>>(X, final_norm_w, (float*)d_out);
}

// Round 8
// 1837.322 us; speedup vs baseline: 1.1813x; 1.0807x over previous
//
#include <hip/hip_runtime.h>
#include <hip/hip_bf16.h>

#define NLAYERS 6
#define B_ 4
#define L_ 1024
#define DM_ 512
#define DI_ 1024
#define NH_ 16
#define HD_ 64
#define NS_ 16
#define CONVD_ 1056
#define DPROJ_ 2096
#define DFF_ 2048
#define ROWS_ (B_*L_)
#define EPS_ 1e-5f
#define NCHUNK_ 16
#define CLEN_ 64

typedef __bf16 bfx8 __attribute__((ext_vector_type(8)));
typedef float f32x4 __attribute__((ext_vector_type(4)));

typedef unsigned int u32_t;
typedef __attribute__((address_space(1))) const u32_t gu32_t;
typedef __attribute__((address_space(3))) u32_t lu32_t;

// async global->LDS, 16B per lane, wave-uniform LDS base + lane*16
__device__ __forceinline__ void gload16(const __bf16* g, __bf16* l){
    __builtin_amdgcn_global_load_lds((gu32_t*)g, (lu32_t*)l, 16, 0, 0);
}

// ---------------- block reduction ----------------
__device__ __forceinline__ float block_reduce_sum(float v){
    __shared__ float sm[8];
    #pragma unroll
    for (int off = 32; off > 0; off >>= 1) v += __shfl_xor(v, off);
    int lane = threadIdx.x & 63, wid = threadIdx.x >> 6;
    if (lane == 0) sm[wid] = v;
    __syncthreads();
    if (threadIdx.x == 0){
        float t = 0.f;
        int nw = blockDim.x >> 6;
        for (int i = 0; i < nw; i++) t += sm[i];
        sm[0] = t;
    }
    __syncthreads();
    return sm[0];
}

// ---------------- copy x -> X ----------------
__global__ void copy_kernel(const float* __restrict__ x, float* __restrict__ X, int n){
    int i = blockIdx.x * blockDim.x + threadIdx.x;
    if (i < n) X[i] = x[i];
}

// ---------------- final rmsnorm -> f32 out ----------------
__global__ void finalnorm_kernel(const float* __restrict__ in, const float* __restrict__ w,
                                 float* __restrict__ out){
    int row = blockIdx.x;
    const float* xr = in + (size_t)row * DM_;
    float ss = 0.f;
    for (int c = threadIdx.x; c < DM_; c += blockDim.x){ float v = xr[c]; ss += v * v; }
    float tot = block_reduce_sum(ss);
    float rsv = rsqrtf(tot / (float)DM_ + EPS_);
    float* orow = out + (size_t)row * DM_;
    for (int c = threadIdx.x; c < DM_; c += blockDim.x)
        orow[c] = xr[c] * rsv * w[c];
}

// ---------------- fused rmsnorm + split-convert: X[row][512] -> A2[row][2*512] hi|lo ----------------
__global__ __launch_bounds__(64) void convAN_kernel(const float* __restrict__ X,
                                                    const float* __restrict__ wv,
                                                    __bf16* __restrict__ A2){
    int row = blockIdx.x, lane = threadIdx.x;
    const float* xr = X + (size_t)row * DM_;
    float v[8];
    {
        float4 a = *reinterpret_cast<const float4*>(xr + lane * 8);
        float4 b = *reinterpret_cast<const float4*>(xr + lane * 8 + 4);
        v[0] = a.x; v[1] = a.y; v[2] = a.z; v[3] = a.w;
        v[4] = b.x; v[5] = b.y; v[6] = b.z; v[7] = b.w;
    }
    float ss = 0.f;
    #pragma unroll
    for (int i = 0; i < 8; i++) ss += v[i] * v[i];
    #pragma unroll
    for (int off = 32; off > 0; off >>= 1) ss += __shfl_xor(ss, off);
    float rsv = rsqrtf(ss / (float)DM_ + EPS_);
    __bf16* ar = A2 + (size_t)row * (2 * DM_);
    #pragma unroll
    for (int i = 0; i < 8; i++){
        float a = v[i] * rsv * wv[lane * 8 + i];
        __bf16 hi = (__bf16)a;
        ar[lane * 8 + i] = hi;
        ar[DM_ + lane * 8 + i] = (__bf16)(a - (float)hi);
    }
}

// ---------------- split-convert A: X(f32,lda) -> A2[M][2K] bf16 (hi|lo), no scaling ----------------
__global__ void convA_kernel(const float* __restrict__ X, int lda,
                             __bf16* __restrict__ A2, int M, int K){
    int idx = blockIdx.x * blockDim.x + threadIdx.x;
    if (idx >= M * K) return;
    int m = idx / K, k = idx - m * K;
    float a = X[(size_t)m * lda + k];
    __bf16 hi = (__bf16)a;
    A2[(size_t)m * (2 * K) + k] = hi;
    A2[(size_t)m * (2 * K) + K + k] = (__bf16)(a - (float)hi);
}

// ---------------- split-convert W: W(f32)[N][K] -> W2[Npad][2K] bf16 (hi|lo), zero pad rows ----------------
__global__ void convW_kernel(const float* __restrict__ W, __bf16* __restrict__ W2,
                             int N, int Npad, int K){
    int idx = blockIdx.x * blockDim.x + threadIdx.x;
    if (idx >= Npad * K) return;
    int n = idx / K, k = idx - n * K;
    size_t ro = (size_t)n * (2 * K);
    if (n >= N){
        W2[ro + k] = (__bf16)0.f; W2[ro + K + k] = (__bf16)0.f;
        return;
    }
    float w = W[(size_t)n * K + k];
    __bf16 hi = (__bf16)w;
    __bf16 lo = (__bf16)(w - (float)hi);
    W2[ro + k] = hi; W2[ro + K + k] = lo;
}

// ---------------- split-K reduce: X += bias + P[0] + P[1] (N=512 rows) ----------------
__global__ void reduceK_kernel(const float* __restrict__ P, const float* __restrict__ bias,
                               float* __restrict__ X, int MN){
    int i = blockIdx.x * blockDim.x + threadIdx.x;        // float4 index
    if (i * 4 >= MN) return;
    float4 a = reinterpret_cast<const float4*>(P)[i];
    float4 b = reinterpret_cast<const float4*>(P + MN)[i];
    float4 x = reinterpret_cast<const float4*>(X)[i];
    float4 r;
    r.x = x.x + a.x + b.x; r.y = x.y + a.y + b.y;
    r.z = x.z + a.z + b.z; r.w = x.w + a.w + b.w;
    if (bias){
        int n = (i * 4) & (DM_ - 1);
        r.x += bias[n]; r.y += bias[n + 1]; r.z += bias[n + 2]; r.w += bias[n + 3];
    }
    reinterpret_cast<float4*>(X)[i] = r;
}

// ---------------- split-bf16 MFMA GEMM: C = A2 x W2^T, hi/lo-chunk K-loop ----------------
// A2[M][2K] (hi|lo), W2[Npad][2K] (hi|lo). Per physical 32-col chunk: stage
// A_hi,A_lo,W_hi,W_lo then acc += Ah*Wh + Ah*Wl + Al*Wh (3 MFMA passes per staged chunk).
// Minimum-2-phase schedule (T3 catalog): stage(t+1) issued BEFORE compute(t);
// single vmcnt(0)+barrier after the MFMA cluster. Double-buffered LDS (48KB at 128x64)
// -> 3 blocks/CU, 12 waves/CU: cross-block TLP covers the post-compute drain (m114).
// Swizzle: source seg q = s^((r>>1)&3), read seg quad^((lm>>1)&3) (conflict-free, R5-proven).
// Grid: 2-D (x = m-tile, y = n-tile); split-K via gridDim.z (chunk-sequential per split).
template<int BM, int BN>
__global__ __launch_bounds__(256, 3) void gemm_mfma_kernel(
    const __bf16* __restrict__ A2, const __bf16* __restrict__ W2,
    const float* __restrict__ bias, const float* __restrict__ resid, int ldr,
    float* __restrict__ Pf,
    float* __restrict__ Cf, int ldc, __bf16* __restrict__ Cs, int csK,
    int M, int N, int K, int act)
{
    constexpr int WTM = BM / 2, WTN = BN / 2;
    constexpr int NI  = WTM / 16;         // M frags per wave
    constexpr int NJ  = WTN / 16;         // N frags per wave
    constexpr int AH  = BM * 32;          // elems per A hi tile
    constexpr int WH  = BN * 32;
    __shared__ __attribute__((aligned(16))) __bf16 As[2][2 * AH];   // [hi|lo]
    __shared__ __attribute__((aligned(16))) __bf16 Ws[2][2 * WH];
    int m0 = blockIdx.x * BM, n0 = blockIdx.y * BN;
    int tid = threadIdx.x;
    int wv = tid >> 6, lane = tid & 63;
    int wm = (wv >> 1) * WTM;
    int wn = (wv & 1) * WTN;
    int lm = lane & 15, quad = lane >> 4;
    int soff = ((quad ^ ((lm >> 1) & 3)) * 8);   // swizzled read segment (per-lane const)
    const int ldA = 2 * K, ldW = 2 * K;
    const int nchunk = K / 32;
    const int ntl = nchunk / gridDim.z;
    const int tb = blockIdx.z * ntl;

    f32x4 acc[NI][NJ] = {};

    // stage physical chunk t (cols t*32..t*32+31, hi and lo) into buffer buf
    auto stage = [&](int buf, int t){
        int kc = t * 32;
        #pragma unroll
        for (int u = 0; u < BM / 64; u++){
            int cb = (wv * (BM / 64) + u) * 64;
            int c = cb + lane;
            int r = c >> 2, s = c & 3, q = s ^ ((r >> 1) & 3);
            const __bf16* ga = A2 + (size_t)(m0 + r) * ldA + kc + q * 8;
            gload16(ga,     &As[buf][cb * 8]);
            gload16(ga + K, &As[buf][AH + cb * 8]);
        }
        #pragma unroll
        for (int u = 0; u < BN / 64; u++){
            int cb = (wv * (BN / 64) + u) * 64;
            int c = cb + lane;
            int r = c >> 2, s = c & 3, q = s ^ ((r >> 1) & 3);
            const __bf16* gw = W2 + (size_t)(n0 + r) * ldW + kc + q * 8;
            gload16(gw,     &Ws[buf][cb * 8]);
            gload16(gw + K, &Ws[buf][WH + cb * 8]);
        }
    };

    stage(0, tb);
    asm volatile("s_waitcnt vmcnt(0)" ::: "memory");
    __builtin_amdgcn_s_barrier();

    int cur = 0;
    for (int tt = 0; tt < ntl; tt++){
        bool staged = (tt + 1 < ntl);
        if (staged) stage(cur ^ 1, tb + tt + 1);

        bfx8 ah[NI], al[NI], bh[NJ], bl[NJ];
        #pragma unroll
        for (int i = 0; i < NI; i++){
            int ra = (wm + i * 16 + lm) * 32 + soff;
            ah[i] = *reinterpret_cast<const bfx8*>(&As[cur][ra]);
            al[i] = *reinterpret_cast<const bfx8*>(&As[cur][AH + ra]);
        }
        #pragma unroll
        for (int j = 0; j < NJ; j++){
            int rb = (wn + j * 16 + lm) * 32 + soff;
            bh[j] = *reinterpret_cast<const bfx8*>(&Ws[cur][rb]);
            bl[j] = *reinterpret_cast<const bfx8*>(&Ws[cur][WH + rb]);
        }

        __builtin_amdgcn_s_setprio(1);
        #pragma unroll
        for (int i = 0; i < NI; i++)
            #pragma unroll
            for (int j = 0; j < NJ; j++)
                acc[i][j] = __builtin_amdgcn_mfma_f32_16x16x32_bf16(
                    ah[i], bh[j], acc[i][j], 0, 0, 0);
        #pragma unroll
        for (int i = 0; i < NI; i++)
            #pragma unroll
            for (int j = 0; j < NJ; j++)
                acc[i][j] = __builtin_amdgcn_mfma_f32_16x16x32_bf16(
                    ah[i], bl[j], acc[i][j], 0, 0, 0);
        #pragma unroll
        for (int i = 0; i < NI; i++)
            #pragma unroll
            for (int j = 0; j < NJ; j++)
                acc[i][j] = __builtin_amdgcn_mfma_f32_16x16x32_bf16(
                    al[i], bh[j], acc[i][j], 0, 0, 0);
        __builtin_amdgcn_s_setprio(0);

        if (staged){
            asm volatile("s_waitcnt vmcnt(0)" ::: "memory");
            __builtin_amdgcn_s_barrier();
        }
        cur ^= 1;
    }

    if (Pf){
        float* pc = Pf + (size_t)blockIdx.z * M * N;
        #pragma unroll
        for (int i = 0; i < NI; i++)
            #pragma unroll
            for (int j = 0; j < NJ; j++){
                int n = n0 + wn + j * 16 + lm;
                #pragma unroll
                for (int r = 0; r < 4; r++){
                    int m = m0 + wm + i * 16 + quad * 4 + r;
                    pc[(size_t)m * N + n] = acc[i][j][r];
                }
            }
        return;
    }

    #pragma unroll
    for (int i = 0; i < NI; i++){
        #pragma unroll
        for (int j = 0; j < NJ; j++){
            int n = n0 + wn + j * 16 + lm;
            if (n < N){
                #pragma unroll
                for (int r = 0; r < 4; r++){
                    int m = m0 + wm + i * 16 + quad * 4 + r;
                    float c = acc[i][j][r];
                    if (bias) c += bias[n];
                    if (act == 1) c = 0.5f * c * (1.f + erff(c * 0.70710678118654752f));
                    if (resid) c += resid[(size_t)m * ldr + n];
                    if (Cf) Cf[(size_t)m * ldc + n] = c;
                    else {
                        __bf16 hi = (__bf16)c;
                        Cs[(size_t)m * (2 * csK) + n] = hi;
                        Cs[(size_t)m * (2 * csK) + csK + n] = (__bf16)(c - (float)hi);
                    }
                }
            }
        }
    }
}

// ---------------- conv+silu for the 32 B/C channels -> BCc[ROWS][32] ----------------
__global__ void bcconv_kernel(const float* __restrict__ ZX, const float* __restrict__ cw,
                              const float* __restrict__ cb, float* __restrict__ BCc){
    int idx = blockIdx.x * blockDim.x + threadIdx.x;
    if (idx >= ROWS_ * 32) return;
    int j = idx & 31;
    int row = idx >> 5;
    int l = row & (L_ - 1);
    float acc = cb[DI_ + j];
    #pragma unroll
    for (int k = 0; k < 4; k++){
        int lt = l + k - 3;
        if (lt >= 0)
            acc += ZX[(size_t)(row + k - 3) * DPROJ_ + (DI_ + DI_) + j] * cw[(DI_ + j) * 4 + k];
    }
    BCc[idx] = acc / (1.f + expf(-acc));
}

// ---------------- dt = softplus(raw + dt_bias); dA = exp(-exp(A_log)*dt) ----------------
__global__ void dt_kernel(const float* __restrict__ ZX, const float* __restrict__ dtb,
                          const float* __restrict__ Alog, float* __restrict__ DT,
                          float* __restrict__ DA){
    int idx = blockIdx.x * blockDim.x + threadIdx.x;
    if (idx >= ROWS_ * NH_) return;
    int h = idx & 15; int row = idx >> 4;
    float v = ZX[(size_t)row * DPROJ_ + (DPROJ_ - NH_) + h] + dtb[h];
    float dtv = (v > 20.f) ? v : log1pf(expf(v));
    DT[idx] = dtv;
    DA[idx] = expf(-expf(Alog[h]) * dtv);
}

// ======== chunked SSM scan (3 phases); blk = b*(NH*NCHUNK)+h*NCHUNK+c ; lane = p ========
__global__ __launch_bounds__(64) void scanA_kernel(const float* __restrict__ ZX,
                                                   const float* __restrict__ BCc,
                                                   const float* __restrict__ DT,
                                                   const float* __restrict__ DA,
                                                   const float* __restrict__ cw,
                                                   const float* __restrict__ cb,
                                                   float* __restrict__ SCH,
                                                   float* __restrict__ PCH,
                                                   float* __restrict__ XWIN){
    int blk = blockIdx.x;
    int c = blk & (NCHUNK_ - 1); int h = (blk >> 4) & (NH_ - 1); int b = blk >> 8;
    int p = threadIdx.x;
    int ch = h * HD_ + p;
    float cw0 = cw[ch * 4 + 0], cw1 = cw[ch * 4 + 1], cw2 = cw[ch * 4 + 2], cw3 = cw[ch * 4 + 3];
    float cbc = cb[ch];
    size_t colx = (size_t)DI_ + ch;
    int t0 = c * CLEN_;
    float w0 = 0.f, w1 = 0.f, w2 = 0.f;
    if (c > 0){
        w0 = ZX[(size_t)(b * L_ + t0 - 3) * DPROJ_ + colx];
        w1 = ZX[(size_t)(b * L_ + t0 - 2) * DPROJ_ + colx];
        w2 = ZX[(size_t)(b * L_ + t0 - 1) * DPROJ_ + colx];
    }
    float* xw = XWIN + (size_t)blk * (3 * 64);
    xw[0 * 64 + p] = w0; xw[1 * 64 + p] = w1; xw[2 * 64 + p] = w2;

    float s[16];
    #pragma unroll
    for (int n = 0; n < 16; n++) s[n] = 0.f;
    float pprod = 1.f;

    for (int tt = 0; tt < CLEN_; tt++){
        int row = b * L_ + t0 + tt;
        size_t rowoff = (size_t)row * DPROJ_;
        float cur = ZX[rowoff + colx];
        float pre = cbc + cw0 * w0 + cw1 * w1 + cw2 * w2 + cw3 * cur;
        float xc = pre / (1.f + expf(-pre));
        w0 = w1; w1 = w2; w2 = cur;
        float dtv = DT[row * NH_ + h];
        float dav = DA[row * NH_ + h];
        pprod *= dav;
        float bc[16];
        const float4* bp = reinterpret_cast<const float4*>(BCc + (size_t)row * 32);
        #pragma unroll
        for (int i = 0; i < 4; i++){
            float4 v = bp[i];
            bc[4 * i + 0] = v.x; bc[4 * i + 1] = v.y; bc[4 * i + 2] = v.z; bc[4 * i + 3] = v.w;
        }
        float coef = dtv * xc;
        #pragma unroll
        for (int n = 0; n < 16; n++)
            s[n] = fmaf(s[n], dav, coef * bc[n]);
    }
    float* sc = SCH + (size_t)blk * 1024 + p * 16;
    #pragma unroll
    for (int i = 0; i < 4; i++)
        *reinterpret_cast<float4*>(sc + 4 * i) = make_float4(s[4*i], s[4*i+1], s[4*i+2], s[4*i+3]);
    if (p == 0) PCH[blk] = pprod;
}

__global__ __launch_bounds__(64) void scanB_kernel(float* __restrict__ SCH,
                                                   const float* __restrict__ PCH){
    int bh = blockIdx.x;
    int p = threadIdx.x;
    float s[16];
    #pragma unroll
    for (int n = 0; n < 16; n++) s[n] = 0.f;
    for (int c = 0; c < NCHUNK_; c++){
        int blk = bh * NCHUNK_ + c;
        float* sc = SCH + (size_t)blk * 1024 + p * 16;
        float loc[16];
        #pragma unroll
        for (int i = 0; i < 4; i++){
            float4 v = *reinterpret_cast<const float4*>(sc + 4 * i);
            loc[4*i] = v.x; loc[4*i+1] = v.y; loc[4*i+2] = v.z; loc[4*i+3] = v.w;
        }
        float P = PCH[blk];
        #pragma unroll
        for (int i = 0; i < 4; i++)
            *reinterpret_cast<float4*>(sc + 4 * i) = make_float4(s[4*i], s[4*i+1], s[4*i+2], s[4*i+3]);
        #pragma unroll
        for (int n = 0; n < 16; n++)
            s[n] = fmaf(P, s[n], loc[n]);
    }
}

__global__ __launch_bounds__(64) void scanC_kernel(float* __restrict__ ZX,
                                                   const float* __restrict__ BCc,
                                                   const float* __restrict__ DT,
                                                   const float* __restrict__ DA,
                                                   const float* __restrict__ cw,
                                                   const float* __restrict__ cb,
                                                   const float* __restrict__ Dh,
                                                   const float* __restrict__ SCH,
                                                   const float* __restrict__ XWIN){
    int blk = blockIdx.x;
    int c = blk & (NCHUNK_ - 1); int h = (blk >> 4) & (NH_ - 1); int b = blk >> 8;
    int p = threadIdx.x;
    int ch = h * HD_ + p;
    float cw0 = cw[ch * 4 + 0], cw1 = cw[ch * 4 + 1], cw2 = cw[ch * 4 + 2], cw3 = cw[ch * 4 + 3];
    float cbc = cb[ch];
    float Dv = Dh[h];
    size_t colx = (size_t)DI_ + ch;
    int t0 = c * CLEN_;
    const float* xw = XWIN + (size_t)blk * (3 * 64);
    float w0 = xw[0 * 64 + p], w1 = xw[1 * 64 + p], w2 = xw[2 * 64 + p];
    const float* sc = SCH + (size_t)blk * 1024 + p * 16;
    float s[16];
    #pragma unroll
    for (int i = 0; i < 4; i++){
        float4 v = *reinterpret_cast<const float4*>(sc + 4 * i);
        s[4*i] = v.x; s[4*i+1] = v.y; s[4*i+2] = v.z; s[4*i+3] = v.w;
    }

    for (int tt = 0; tt < CLEN_; tt++){
        int row = b * L_ + t0 + tt;
        size_t rowoff = (size_t)row * DPROJ_;
        float cur = ZX[rowoff + colx];
        float pre = cbc + cw0 * w0 + cw1 * w1 + cw2 * w2 + cw3 * cur;
        float xc = pre / (1.f + expf(-pre));
        w0 = w1; w1 = w2; w2 = cur;
        float dtv = DT[row * NH_ + h];
        float dav = DA[row * NH_ + h];
        float bc[32];
        const float4* bp = reinterpret_cast<const float4*>(BCc + (size_t)row * 32);
        #pragma unroll
        for (int i = 0; i < 8; i++){
            float4 v = bp[i];
            bc[4 * i + 0] = v.x; bc[4 * i + 1] = v.y; bc[4 * i + 2] = v.z; bc[4 * i + 3] = v.w;
        }
        float coef = dtv * xc;
        float y = 0.f;
        #pragma unroll
        for (int n = 0; n < 16; n++){
            s[n] = fmaf(s[n], dav, coef * bc[n]);
            y += s[n] * bc[16 + n];
        }
        ZX[rowoff + colx] = fmaf(Dv, xc, y);
    }
}

// ---------------- gated rmsnorm in place on ZX ----------------
__global__ void gatenorm_kernel(float* __restrict__ ZX, const float* __restrict__ gw){
    int row = blockIdx.x;
    float* zr = ZX + (size_t)row * DPROJ_;
    float* yr = zr + DI_;
    float ss = 0.f;
    for (int cc = threadIdx.x; cc < DI_; cc += blockDim.x){
        float z = zr[cc];
        float v = yr[cc] * (z / (1.f + expf(-z)));
        yr[cc] = v;
        ss += v * v;
    }
    float tot = block_reduce_sum(ss);
    float rsv = rsqrtf(tot / (float)DI_ + EPS_);
    for (int cc = threadIdx.x; cc < DI_; cc += blockDim.x)
        yr[cc] = yr[cc] * rsv * gw[cc];
}

extern "C" void kernel_launch(void* const* d_in, const int* in_sizes, int n_in,
                              void* d_out, int out_size, void* d_ws, size_t ws_size,
                              hipStream_t stream){
    const float* x_in        = (const float*)d_in[0];
    const float* in_proj_w   = (const float*)d_in[1];
    const float* conv_w      = (const float*)d_in[2];
    const float* conv_b      = (const float*)d_in[3];
    const float* dt_bias     = (const float*)d_in[4];
    const float* A_log       = (const float*)d_in[5];
    const float* D_ssm       = (const float*)d_in[6];
    const float* gnorm_w     = (const float*)d_in[7];
    const float* out_proj_w  = (const float*)d_in[8];
    const float* ffn_w1      = (const float*)d_in[9];
    const float* ffn_b1      = (const float*)d_in[10];
    const float* ffn_w2      = (const float*)d_in[11];
    const float* ffn_b2      = (const float*)d_in[12];
    const float* norm_mamba_w= (const float*)d_in[13];
    const float* norm_ffn_w  = (const float*)d_in[14];
    const float* final_norm_w= (const float*)d_in[15];

    // ---- workspace layout (same offsets as R5-R7) ----
    float* X    = (float*)d_ws;                       // 2,097,152 f
    float* RS   = X    + 2097152;                     // 4096 (unused, kept for layout)
    float* BCc  = RS   + 4096;                        // 131072
    float* DT   = BCc  + 131072;                      // 65536
    float* DA   = DT   + 65536;                       // 65536
    float* SCH  = DA   + 65536;                       // 1,048,576
    float* PCH  = SCH  + 1048576;                     // 1024
    float* XWIN = PCH  + 1024;                        // 196,608
    __bf16* A2  = (__bf16*)(XWIN + 196608);           // 8,388,608 bf16 (max M x 2K, K=1024)
    __bf16* W2  = A2 + 8388608;                       // region 3,342,336 bf16 (used: <=2176x2K)
    float* ZX   = (float*)(W2 + 3342336);             // 4096 x 2096 f32 (also H-split region)
    __bf16* Hs  = (__bf16*)ZX;                        // 4096 x 4096 bf16 (ffn hidden, hi|lo)
    // split-K partial buffers (aliased, each 2 x 4096 x 512 f32 = 16 MiB):
    float* PART_OP = ZX;                              // out_proj: ZX dead after convA
    float* PART_F2 = (float*)A2;                      // ffn2: A2 unused (A = Hs)

    const int NBLK = B_ * NH_ * NCHUNK_;              // 1024

    copy_kernel<<<(ROWS_ * DM_ + 255) / 256, 256, 0, stream>>>(x_in, X, ROWS_ * DM_);

    for (int l = 0; l < NLAYERS; l++){
        const float* cwl = conv_w + (size_t)l * CONVD_ * 4;
        const float* cbl = conv_b + (size_t)l * CONVD_;

        // ---- mamba: fused rmsnorm+convert, then MFMA in_proj ----
        convAN_kernel<<<ROWS_, 64, 0, stream>>>(X, norm_mamba_w + (size_t)l * DM_, A2);
        convW_kernel<<<(2176 * DM_ + 255) / 256, 256, 0, stream>>>(
            in_proj_w + (size_t)l * DPROJ_ * DM_, W2, DPROJ_, 2176, DM_);
        {
            dim3 g(ROWS_ / 128, 2176 / 64, 1);
            gemm_mfma_kernel<128,64><<<g, 256, 0, stream>>>(
                A2, W2, nullptr, nullptr, 0, nullptr,
                ZX, DPROJ_, nullptr, 0, ROWS_, DPROJ_, DM_, 0);
        }

        bcconv_kernel<<<(ROWS_ * 32 + 255) / 256, 256, 0, stream>>>(ZX, cwl, cbl, BCc);
        dt_kernel<<<(ROWS_ * NH_ + 255) / 256, 256, 0, stream>>>(
            ZX, dt_bias + (size_t)l * NH_, A_log + (size_t)l * NH_, DT, DA);

        scanA_kernel<<<NBLK, 64, 0, stream>>>(ZX, BCc, DT, DA, cwl, cbl, SCH, PCH, XWIN);
        scanB_kernel<<<B_ * NH_, 64, 0, stream>>>(SCH, PCH);
        scanC_kernel<<<NBLK, 64, 0, stream>>>(ZX, BCc, DT, DA, cwl, cbl,
                                              D_ssm + (size_t)l * NH_, SCH, XWIN);

        gatenorm_kernel<<<ROWS_, 256, 0, stream>>>(ZX, gnorm_w + (size_t)l * DI_);

        // ---- out_proj (split-K x2, 128x64 tiles -> partials -> reduce into X) ----
        convA_kernel<<<(ROWS_ * DI_ + 255) / 256, 256, 0, stream>>>(
            ZX + DI_, DPROJ_, A2, ROWS_, DI_);
        convW_kernel<<<(DM_ * DI_ + 255) / 256, 256, 0, stream>>>(
            out_proj_w + (size_t)l * DM_ * DI_, W2, DM_, DM_, DI_);
        {
            dim3 g(ROWS_ / 128, DM_ / 64, 2);
            gemm_mfma_kernel<128,64><<<g, 256, 0, stream>>>(
                A2, W2, nullptr, nullptr, 0, PART_OP,
                nullptr, 0, nullptr, 0, ROWS_, DM_, DI_, 0);
        }
        reduceK_kernel<<<(ROWS_ * DM_ / 4 + 255) / 256, 256, 0, stream>>>(
            PART_OP, nullptr, X, ROWS_ * DM_);

        // ---- ffn: fused norm+convert, ffn1 emits bf16 split hidden, ffn2 split-K + reduce ----
        convAN_kernel<<<ROWS_, 64, 0, stream>>>(X, norm_ffn_w + (size_t)l * DM_, A2);
        convW_kernel<<<(DFF_ * DM_ + 255) / 256, 256, 0, stream>>>(
            ffn_w1 + (size_t)l * DFF_ * DM_, W2, DFF_, DFF_, DM_);
        {
            dim3 g(ROWS_ / 128, DFF_ / 64, 1);
            gemm_mfma_kernel<128,64><<<g, 256, 0, stream>>>(
                A2, W2, ffn_b1 + (size_t)l * DFF_, nullptr, 0, nullptr,
                nullptr, 0, Hs, DFF_, ROWS_, DFF_, DM_, 1);
        }
        convW_kernel<<<(DM_ * DFF_ + 255) / 256, 256, 0, stream>>>(
            ffn_w2 + (size_t)l * DM_ * DFF_, W2, DM_, DM_, DFF_);
        {
            dim3 g(ROWS_ / 128, DM_ / 64, 2);
            gemm_mfma_kernel<128,64><<<g, 256, 0, stream>>>(
                Hs, W2, nullptr, nullptr, 0, PART_F2,
                nullptr, 0, nullptr, 0, ROWS_, DM_, DFF_, 0);
        }
        reduceK_kernel<<<(ROWS_ * DM_ / 4 + 255) / 256, 256, 0, stream>>>(
            PART_F2, ffn_b2 + (size_t)l * DM_, X, ROWS_ * DM_);
    }

    finalnorm_kernel<<<ROWS_, 256, 0, stream>>>(X, final_norm_w, (float*)d_out);
}

// Round 9
// 1809.867 us; speedup vs baseline: 1.1992x; 1.0152x over previous
//
#include <hip/hip_runtime.h>
#include <hip/hip_bf16.h>

#define NLAYERS 6
#define B_ 4
#define L_ 1024
#define DM_ 512
#define DI_ 1024
#define NH_ 16
#define HD_ 64
#define NS_ 16
#define CONVD_ 1056
#define DPROJ_ 2096
#define DFF_ 2048
#define ROWS_ (B_*L_)
#define EPS_ 1e-5f
#define NCHUNK_ 16
#define CLEN_ 64

typedef __bf16 bfx8 __attribute__((ext_vector_type(8)));
typedef float f32x4 __attribute__((ext_vector_type(4)));

typedef unsigned int u32_t;
typedef __attribute__((address_space(1))) const u32_t gu32_t;
typedef __attribute__((address_space(3))) u32_t lu32_t;

// async global->LDS, 16B per lane, wave-uniform LDS base + lane*16
__device__ __forceinline__ void gload16(const __bf16* g, __bf16* l){
    __builtin_amdgcn_global_load_lds((gu32_t*)g, (lu32_t*)l, 16, 0, 0);
}

// ---------------- block reduction ----------------
__device__ __forceinline__ float block_reduce_sum(float v){
    __shared__ float sm[8];
    #pragma unroll
    for (int off = 32; off > 0; off >>= 1) v += __shfl_xor(v, off);
    int lane = threadIdx.x & 63, wid = threadIdx.x >> 6;
    if (lane == 0) sm[wid] = v;
    __syncthreads();
    if (threadIdx.x == 0){
        float t = 0.f;
        int nw = blockDim.x >> 6;
        for (int i = 0; i < nw; i++) t += sm[i];
        sm[0] = t;
    }
    __syncthreads();
    return sm[0];
}

// ---------------- copy x -> X ----------------
__global__ void copy_kernel(const float* __restrict__ x, float* __restrict__ X, int n){
    int i = blockIdx.x * blockDim.x + threadIdx.x;
    if (i < n) X[i] = x[i];
}

// ---------------- final rmsnorm -> f32 out ----------------
__global__ void finalnorm_kernel(const float* __restrict__ in, const float* __restrict__ w,
                                 float* __restrict__ out){
    int row = blockIdx.x;
    const float* xr = in + (size_t)row * DM_;
    float ss = 0.f;
    for (int c = threadIdx.x; c < DM_; c += blockDim.x){ float v = xr[c]; ss += v * v; }
    float tot = block_reduce_sum(ss);
    float rsv = rsqrtf(tot / (float)DM_ + EPS_);
    float* orow = out + (size_t)row * DM_;
    for (int c = threadIdx.x; c < DM_; c += blockDim.x)
        orow[c] = xr[c] * rsv * w[c];
}

// ---------------- fused rmsnorm + split-convert: X[row][512] -> A2[row][2*512] hi|lo ----------------
__global__ __launch_bounds__(64) void convAN_kernel(const float* __restrict__ X,
                                                    const float* __restrict__ wv,
                                                    __bf16* __restrict__ A2){
    int row = blockIdx.x, lane = threadIdx.x;
    const float* xr = X + (size_t)row * DM_;
    float v[8];
    {
        float4 a = *reinterpret_cast<const float4*>(xr + lane * 8);
        float4 b = *reinterpret_cast<const float4*>(xr + lane * 8 + 4);
        v[0] = a.x; v[1] = a.y; v[2] = a.z; v[3] = a.w;
        v[4] = b.x; v[5] = b.y; v[6] = b.z; v[7] = b.w;
    }
    float ss = 0.f;
    #pragma unroll
    for (int i = 0; i < 8; i++) ss += v[i] * v[i];
    #pragma unroll
    for (int off = 32; off > 0; off >>= 1) ss += __shfl_xor(ss, off);
    float rsv = rsqrtf(ss / (float)DM_ + EPS_);
    __bf16* ar = A2 + (size_t)row * (2 * DM_);
    #pragma unroll
    for (int i = 0; i < 8; i++){
        float a = v[i] * rsv * wv[lane * 8 + i];
        __bf16 hi = (__bf16)a;
        ar[lane * 8 + i] = hi;
        ar[DM_ + lane * 8 + i] = (__bf16)(a - (float)hi);
    }
}

// ---------------- split-convert A: X(f32,lda) -> A2[M][2K] bf16 (hi|lo), no scaling ----------------
__global__ void convA_kernel(const float* __restrict__ X, int lda,
                             __bf16* __restrict__ A2, int M, int K){
    int idx = blockIdx.x * blockDim.x + threadIdx.x;
    if (idx >= M * K) return;
    int m = idx / K, k = idx - m * K;
    float a = X[(size_t)m * lda + k];
    __bf16 hi = (__bf16)a;
    A2[(size_t)m * (2 * K) + k] = hi;
    A2[(size_t)m * (2 * K) + K + k] = (__bf16)(a - (float)hi);
}

// ---------------- split-convert W: W(f32)[N][K] -> W2[Npad][2K] bf16 (hi|lo), zero pad rows ----------------
__global__ void convW_kernel(const float* __restrict__ W, __bf16* __restrict__ W2,
                             int N, int Npad, int K){
    int idx = blockIdx.x * blockDim.x + threadIdx.x;
    if (idx >= Npad * K) return;
    int n = idx / K, k = idx - n * K;
    size_t ro = (size_t)n * (2 * K);
    if (n >= N){
        W2[ro + k] = (__bf16)0.f; W2[ro + K + k] = (__bf16)0.f;
        return;
    }
    float w = W[(size_t)n * K + k];
    __bf16 hi = (__bf16)w;
    __bf16 lo = (__bf16)(w - (float)hi);
    W2[ro + k] = hi; W2[ro + K + k] = lo;
}

// ---------------- split-K reduce: X += bias + P[0] + P[1] (N=512 rows) ----------------
__global__ void reduceK_kernel(const float* __restrict__ P, const float* __restrict__ bias,
                               float* __restrict__ X, int MN){
    int i = blockIdx.x * blockDim.x + threadIdx.x;        // float4 index
    if (i * 4 >= MN) return;
    float4 a = reinterpret_cast<const float4*>(P)[i];
    float4 b = reinterpret_cast<const float4*>(P + MN)[i];
    float4 x = reinterpret_cast<const float4*>(X)[i];
    float4 r;
    r.x = x.x + a.x + b.x; r.y = x.y + a.y + b.y;
    r.z = x.z + a.z + b.z; r.w = x.w + a.w + b.w;
    if (bias){
        int n = (i * 4) & (DM_ - 1);
        r.x += bias[n]; r.y += bias[n + 1]; r.z += bias[n + 2]; r.w += bias[n + 3];
    }
    reinterpret_cast<float4*>(X)[i] = r;
}

// ---------------- split-bf16 MFMA GEMM: C = A2 x W2^T, hi/lo-chunk K-loop ----------------
// A2[M][2K] (hi|lo), W2[Npad][2K] (hi|lo). Per physical 32-col chunk: stage
// A_hi,A_lo,W_hi,W_lo then acc += Ah*Wh + Ah*Wl + Al*Wh (3 MFMA passes per staged chunk).
// R8-proven minimum-2-phase schedule: stage(t+1) issued BEFORE compute(t);
// single vmcnt(0)+barrier after the MFMA cluster. Double-buffered LDS.
// BN=128 (in_proj/ffn1): wave tile 64x64, MFMA:ds_read = 3.0 (-33% LDS traffic/MFMA),
//   64KB LDS -> 2 blocks/CU, launch_bounds(256,2) to avoid spill (~160 VGPR).
// BN=64 (split-K GEMMs): wave tile 64x32, 48KB -> 3 blocks/CU, launch_bounds(256,3).
// Swizzle: source seg q = s^((r>>1)&3), read seg quad^((lm>>1)&3) (conflict-free, R5/R8-proven).
// Grid: 2-D (x = m-tile, y = n-tile); split-K via gridDim.z (chunk-sequential per split).
template<int BM, int BN>
__global__ __launch_bounds__(256, (BN == 128) ? 2 : 3) void gemm_mfma_kernel(
    const __bf16* __restrict__ A2, const __bf16* __restrict__ W2,
    const float* __restrict__ bias, const float* __restrict__ resid, int ldr,
    float* __restrict__ Pf,
    float* __restrict__ Cf, int ldc, __bf16* __restrict__ Cs, int csK,
    int M, int N, int K, int act)
{
    constexpr int WTM = BM / 2, WTN = BN / 2;
    constexpr int NI  = WTM / 16;         // M frags per wave
    constexpr int NJ  = WTN / 16;         // N frags per wave
    constexpr int AH  = BM * 32;          // elems per A hi tile
    constexpr int WH  = BN * 32;
    __shared__ __attribute__((aligned(16))) __bf16 As[2][2 * AH];   // [hi|lo]
    __shared__ __attribute__((aligned(16))) __bf16 Ws[2][2 * WH];
    int m0 = blockIdx.x * BM, n0 = blockIdx.y * BN;
    int tid = threadIdx.x;
    int wv = tid >> 6, lane = tid & 63;
    int wm = (wv >> 1) * WTM;
    int wn = (wv & 1) * WTN;
    int lm = lane & 15, quad = lane >> 4;
    int soff = ((quad ^ ((lm >> 1) & 3)) * 8);   // swizzled read segment (per-lane const)
    const int ldA = 2 * K, ldW = 2 * K;
    const int nchunk = K / 32;
    const int ntl = nchunk / gridDim.z;
    const int tb = blockIdx.z * ntl;

    f32x4 acc[NI][NJ] = {};

    // stage physical chunk t (cols t*32..t*32+31, hi and lo) into buffer buf
    auto stage = [&](int buf, int t){
        int kc = t * 32;
        #pragma unroll
        for (int u = 0; u < BM / 64; u++){
            int cb = (wv * (BM / 64) + u) * 64;
            int c = cb + lane;
            int r = c >> 2, s = c & 3, q = s ^ ((r >> 1) & 3);
            const __bf16* ga = A2 + (size_t)(m0 + r) * ldA + kc + q * 8;
            gload16(ga,     &As[buf][cb * 8]);
            gload16(ga + K, &As[buf][AH + cb * 8]);
        }
        #pragma unroll
        for (int u = 0; u < BN / 64; u++){
            int cb = (wv * (BN / 64) + u) * 64;
            int c = cb + lane;
            int r = c >> 2, s = c & 3, q = s ^ ((r >> 1) & 3);
            const __bf16* gw = W2 + (size_t)(n0 + r) * ldW + kc + q * 8;
            gload16(gw,     &Ws[buf][cb * 8]);
            gload16(gw + K, &Ws[buf][WH + cb * 8]);
        }
    };

    stage(0, tb);
    asm volatile("s_waitcnt vmcnt(0)" ::: "memory");
    __builtin_amdgcn_s_barrier();

    int cur = 0;
    for (int tt = 0; tt < ntl; tt++){
        bool staged = (tt + 1 < ntl);
        if (staged) stage(cur ^ 1, tb + tt + 1);

        bfx8 ah[NI], al[NI], bh[NJ], bl[NJ];
        #pragma unroll
        for (int i = 0; i < NI; i++){
            int ra = (wm + i * 16 + lm) * 32 + soff;
            ah[i] = *reinterpret_cast<const bfx8*>(&As[cur][ra]);
            al[i] = *reinterpret_cast<const bfx8*>(&As[cur][AH + ra]);
        }
        #pragma unroll
        for (int j = 0; j < NJ; j++){
            int rb = (wn + j * 16 + lm) * 32 + soff;
            bh[j] = *reinterpret_cast<const bfx8*>(&Ws[cur][rb]);
            bl[j] = *reinterpret_cast<const bfx8*>(&Ws[cur][WH + rb]);
        }

        __builtin_amdgcn_s_setprio(1);
        #pragma unroll
        for (int i = 0; i < NI; i++)
            #pragma unroll
            for (int j = 0; j < NJ; j++)
                acc[i][j] = __builtin_amdgcn_mfma_f32_16x16x32_bf16(
                    ah[i], bh[j], acc[i][j], 0, 0, 0);
        #pragma unroll
        for (int i = 0; i < NI; i++)
            #pragma unroll
            for (int j = 0; j < NJ; j++)
                acc[i][j] = __builtin_amdgcn_mfma_f32_16x16x32_bf16(
                    ah[i], bl[j], acc[i][j], 0, 0, 0);
        #pragma unroll
        for (int i = 0; i < NI; i++)
            #pragma unroll
            for (int j = 0; j < NJ; j++)
                acc[i][j] = __builtin_amdgcn_mfma_f32_16x16x32_bf16(
                    al[i], bh[j], acc[i][j], 0, 0, 0);
        __builtin_amdgcn_s_setprio(0);

        if (staged){
            asm volatile("s_waitcnt vmcnt(0)" ::: "memory");
            __builtin_amdgcn_s_barrier();
        }
        cur ^= 1;
    }

    if (Pf){
        float* pc = Pf + (size_t)blockIdx.z * M * N;
        #pragma unroll
        for (int i = 0; i < NI; i++)
            #pragma unroll
            for (int j = 0; j < NJ; j++){
                int n = n0 + wn + j * 16 + lm;
                #pragma unroll
                for (int r = 0; r < 4; r++){
                    int m = m0 + wm + i * 16 + quad * 4 + r;
                    pc[(size_t)m * N + n] = acc[i][j][r];
                }
            }
        return;
    }

    #pragma unroll
    for (int i = 0; i < NI; i++){
        #pragma unroll
        for (int j = 0; j < NJ; j++){
            int n = n0 + wn + j * 16 + lm;
            if (n < N){
                #pragma unroll
                for (int r = 0; r < 4; r++){
                    int m = m0 + wm + i * 16 + quad * 4 + r;
                    float c = acc[i][j][r];
                    if (bias) c += bias[n];
                    if (act == 1) c = 0.5f * c * (1.f + erff(c * 0.70710678118654752f));
                    if (resid) c += resid[(size_t)m * ldr + n];
                    if (Cf) Cf[(size_t)m * ldc + n] = c;
                    else {
                        __bf16 hi = (__bf16)c;
                        Cs[(size_t)m * (2 * csK) + n] = hi;
                        Cs[(size_t)m * (2 * csK) + csK + n] = (__bf16)(c - (float)hi);
                    }
                }
            }
        }
    }
}

// ---------------- conv+silu for the 32 B/C channels -> BCc[ROWS][32] ----------------
__global__ void bcconv_kernel(const float* __restrict__ ZX, const float* __restrict__ cw,
                              const float* __restrict__ cb, float* __restrict__ BCc){
    int idx = blockIdx.x * blockDim.x + threadIdx.x;
    if (idx >= ROWS_ * 32) return;
    int j = idx & 31;
    int row = idx >> 5;
    int l = row & (L_ - 1);
    float acc = cb[DI_ + j];
    #pragma unroll
    for (int k = 0; k < 4; k++){
        int lt = l + k - 3;
        if (lt >= 0)
            acc += ZX[(size_t)(row + k - 3) * DPROJ_ + (DI_ + DI_) + j] * cw[(DI_ + j) * 4 + k];
    }
    BCc[idx] = acc / (1.f + expf(-acc));
}

// ---------------- dt = softplus(raw + dt_bias); dA = exp(-exp(A_log)*dt) ----------------
__global__ void dt_kernel(const float* __restrict__ ZX, const float* __restrict__ dtb,
                          const float* __restrict__ Alog, float* __restrict__ DT,
                          float* __restrict__ DA){
    int idx = blockIdx.x * blockDim.x + threadIdx.x;
    if (idx >= ROWS_ * NH_) return;
    int h = idx & 15; int row = idx >> 4;
    float v = ZX[(size_t)row * DPROJ_ + (DPROJ_ - NH_) + h] + dtb[h];
    float dtv = (v > 20.f) ? v : log1pf(expf(v));
    DT[idx] = dtv;
    DA[idx] = expf(-expf(Alog[h]) * dtv);
}

// ======== chunked SSM scan (3 phases); blk = b*(NH*NCHUNK)+h*NCHUNK+c ; lane = p ========
__global__ __launch_bounds__(64) void scanA_kernel(const float* __restrict__ ZX,
                                                   const float* __restrict__ BCc,
                                                   const float* __restrict__ DT,
                                                   const float* __restrict__ DA,
                                                   const float* __restrict__ cw,
                                                   const float* __restrict__ cb,
                                                   float* __restrict__ SCH,
                                                   float* __restrict__ PCH,
                                                   float* __restrict__ XWIN){
    int blk = blockIdx.x;
    int c = blk & (NCHUNK_ - 1); int h = (blk >> 4) & (NH_ - 1); int b = blk >> 8;
    int p = threadIdx.x;
    int ch = h * HD_ + p;
    float cw0 = cw[ch * 4 + 0], cw1 = cw[ch * 4 + 1], cw2 = cw[ch * 4 + 2], cw3 = cw[ch * 4 + 3];
    float cbc = cb[ch];
    size_t colx = (size_t)DI_ + ch;
    int t0 = c * CLEN_;
    float w0 = 0.f, w1 = 0.f, w2 = 0.f;
    if (c > 0){
        w0 = ZX[(size_t)(b * L_ + t0 - 3) * DPROJ_ + colx];
        w1 = ZX[(size_t)(b * L_ + t0 - 2) * DPROJ_ + colx];
        w2 = ZX[(size_t)(b * L_ + t0 - 1) * DPROJ_ + colx];
    }
    float* xw = XWIN + (size_t)blk * (3 * 64);
    xw[0 * 64 + p] = w0; xw[1 * 64 + p] = w1; xw[2 * 64 + p] = w2;

    float s[16];
    #pragma unroll
    for (int n = 0; n < 16; n++) s[n] = 0.f;
    float pprod = 1.f;

    for (int tt = 0; tt < CLEN_; tt++){
        int row = b * L_ + t0 + tt;
        size_t rowoff = (size_t)row * DPROJ_;
        float cur = ZX[rowoff + colx];
        float pre = cbc + cw0 * w0 + cw1 * w1 + cw2 * w2 + cw3 * cur;
        float xc = pre / (1.f + expf(-pre));
        w0 = w1; w1 = w2; w2 = cur;
        float dtv = DT[row * NH_ + h];
        float dav = DA[row * NH_ + h];
        pprod *= dav;
        float bc[16];
        const float4* bp = reinterpret_cast<const float4*>(BCc + (size_t)row * 32);
        #pragma unroll
        for (int i = 0; i < 4; i++){
            float4 v = bp[i];
            bc[4 * i + 0] = v.x; bc[4 * i + 1] = v.y; bc[4 * i + 2] = v.z; bc[4 * i + 3] = v.w;
        }
        float coef = dtv * xc;
        #pragma unroll
        for (int n = 0; n < 16; n++)
            s[n] = fmaf(s[n], dav, coef * bc[n]);
    }
    float* sc = SCH + (size_t)blk * 1024 + p * 16;
    #pragma unroll
    for (int i = 0; i < 4; i++)
        *reinterpret_cast<float4*>(sc + 4 * i) = make_float4(s[4*i], s[4*i+1], s[4*i+2], s[4*i+3]);
    if (p == 0) PCH[blk] = pprod;
}

__global__ __launch_bounds__(64) void scanB_kernel(float* __restrict__ SCH,
                                                   const float* __restrict__ PCH){
    int bh = blockIdx.x;
    int p = threadIdx.x;
    float s[16];
    #pragma unroll
    for (int n = 0; n < 16; n++) s[n] = 0.f;
    for (int c = 0; c < NCHUNK_; c++){
        int blk = bh * NCHUNK_ + c;
        float* sc = SCH + (size_t)blk * 1024 + p * 16;
        float loc[16];
        #pragma unroll
        for (int i = 0; i < 4; i++){
            float4 v = *reinterpret_cast<const float4*>(sc + 4 * i);
            loc[4*i] = v.x; loc[4*i+1] = v.y; loc[4*i+2] = v.z; loc[4*i+3] = v.w;
        }
        float P = PCH[blk];
        #pragma unroll
        for (int i = 0; i < 4; i++)
            *reinterpret_cast<float4*>(sc + 4 * i) = make_float4(s[4*i], s[4*i+1], s[4*i+2], s[4*i+3]);
        #pragma unroll
        for (int n = 0; n < 16; n++)
            s[n] = fmaf(P, s[n], loc[n]);
    }
}

__global__ __launch_bounds__(64) void scanC_kernel(float* __restrict__ ZX,
                                                   const float* __restrict__ BCc,
                                                   const float* __restrict__ DT,
                                                   const float* __restrict__ DA,
                                                   const float* __restrict__ cw,
                                                   const float* __restrict__ cb,
                                                   const float* __restrict__ Dh,
                                                   const float* __restrict__ SCH,
                                                   const float* __restrict__ XWIN){
    int blk = blockIdx.x;
    int c = blk & (NCHUNK_ - 1); int h = (blk >> 4) & (NH_ - 1); int b = blk >> 8;
    int p = threadIdx.x;
    int ch = h * HD_ + p;
    float cw0 = cw[ch * 4 + 0], cw1 = cw[ch * 4 + 1], cw2 = cw[ch * 4 + 2], cw3 = cw[ch * 4 + 3];
    float cbc = cb[ch];
    float Dv = Dh[h];
    size_t colx = (size_t)DI_ + ch;
    int t0 = c * CLEN_;
    const float* xw = XWIN + (size_t)blk * (3 * 64);
    float w0 = xw[0 * 64 + p], w1 = xw[1 * 64 + p], w2 = xw[2 * 64 + p];
    const float* sc = SCH + (size_t)blk * 1024 + p * 16;
    float s[16];
    #pragma unroll
    for (int i = 0; i < 4; i++){
        float4 v = *reinterpret_cast<const float4*>(sc + 4 * i);
        s[4*i] = v.x; s[4*i+1] = v.y; s[4*i+2] = v.z; s[4*i+3] = v.w;
    }

    for (int tt = 0; tt < CLEN_; tt++){
        int row = b * L_ + t0 + tt;
        size_t rowoff = (size_t)row * DPROJ_;
        float cur = ZX[rowoff + colx];
        float pre = cbc + cw0 * w0 + cw1 * w1 + cw2 * w2 + cw3 * cur;
        float xc = pre / (1.f + expf(-pre));
        w0 = w1; w1 = w2; w2 = cur;
        float dtv = DT[row * NH_ + h];
        float dav = DA[row * NH_ + h];
        float bc[32];
        const float4* bp = reinterpret_cast<const float4*>(BCc + (size_t)row * 32);
        #pragma unroll
        for (int i = 0; i < 8; i++){
            float4 v = bp[i];
            bc[4 * i + 0] = v.x; bc[4 * i + 1] = v.y; bc[4 * i + 2] = v.z; bc[4 * i + 3] = v.w;
        }
        float coef = dtv * xc;
        float y = 0.f;
        #pragma unroll
        for (int n = 0; n < 16; n++){
            s[n] = fmaf(s[n], dav, coef * bc[n]);
            y += s[n] * bc[16 + n];
        }
        ZX[rowoff + colx] = fmaf(Dv, xc, y);
    }
}

// ---------------- gated rmsnorm in place on ZX ----------------
__global__ void gatenorm_kernel(float* __restrict__ ZX, const float* __restrict__ gw){
    int row = blockIdx.x;
    float* zr = ZX + (size_t)row * DPROJ_;
    float* yr = zr + DI_;
    float ss = 0.f;
    for (int cc = threadIdx.x; cc < DI_; cc += blockDim.x){
        float z = zr[cc];
        float v = yr[cc] * (z / (1.f + expf(-z)));
        yr[cc] = v;
        ss += v * v;
    }
    float tot = block_reduce_sum(ss);
    float rsv = rsqrtf(tot / (float)DI_ + EPS_);
    for (int cc = threadIdx.x; cc < DI_; cc += blockDim.x)
        yr[cc] = yr[cc] * rsv * gw[cc];
}

extern "C" void kernel_launch(void* const* d_in, const int* in_sizes, int n_in,
                              void* d_out, int out_size, void* d_ws, size_t ws_size,
                              hipStream_t stream){
    const float* x_in        = (const float*)d_in[0];
    const float* in_proj_w   = (const float*)d_in[1];
    const float* conv_w      = (const float*)d_in[2];
    const float* conv_b      = (const float*)d_in[3];
    const float* dt_bias     = (const float*)d_in[4];
    const float* A_log       = (const float*)d_in[5];
    const float* D_ssm       = (const float*)d_in[6];
    const float* gnorm_w     = (const float*)d_in[7];
    const float* out_proj_w  = (const float*)d_in[8];
    const float* ffn_w1      = (const float*)d_in[9];
    const float* ffn_b1      = (const float*)d_in[10];
    const float* ffn_w2      = (const float*)d_in[11];
    const float* ffn_b2      = (const float*)d_in[12];
    const float* norm_mamba_w= (const float*)d_in[13];
    const float* norm_ffn_w  = (const float*)d_in[14];
    const float* final_norm_w= (const float*)d_in[15];

    // ---- workspace layout (same offsets as R5-R8) ----
    float* X    = (float*)d_ws;                       // 2,097,152 f
    float* RS   = X    + 2097152;                     // 4096 (unused, kept for layout)
    float* BCc  = RS   + 4096;                        // 131072
    float* DT   = BCc  + 131072;                      // 65536
    float* DA   = DT   + 65536;                       // 65536
    float* SCH  = DA   + 65536;                       // 1,048,576
    float* PCH  = SCH  + 1048576;                     // 1024
    float* XWIN = PCH  + 1024;                        // 196,608
    __bf16* A2  = (__bf16*)(XWIN + 196608);           // 8,388,608 bf16 (max M x 2K, K=1024)
    __bf16* W2  = A2 + 8388608;                       // region 3,342,336 bf16 (used: <=2176x2K)
    float* ZX   = (float*)(W2 + 3342336);             // 4096 x 2096 f32 (also H-split region)
    __bf16* Hs  = (__bf16*)ZX;                        // 4096 x 4096 bf16 (ffn hidden, hi|lo)
    // split-K partial buffers (aliased, each 2 x 4096 x 512 f32 = 16 MiB):
    float* PART_OP = ZX;                              // out_proj: ZX dead after convA
    float* PART_F2 = (float*)A2;                      // ffn2: A2 unused (A = Hs)

    const int NBLK = B_ * NH_ * NCHUNK_;              // 1024

    copy_kernel<<<(ROWS_ * DM_ + 255) / 256, 256, 0, stream>>>(x_in, X, ROWS_ * DM_);

    for (int l = 0; l < NLAYERS; l++){
        const float* cwl = conv_w + (size_t)l * CONVD_ * 4;
        const float* cbl = conv_b + (size_t)l * CONVD_;

        // ---- mamba: fused rmsnorm+convert, then MFMA in_proj (128x128 tiles) ----
        convAN_kernel<<<ROWS_, 64, 0, stream>>>(X, norm_mamba_w + (size_t)l * DM_, A2);
        convW_kernel<<<(2176 * DM_ + 255) / 256, 256, 0, stream>>>(
            in_proj_w + (size_t)l * DPROJ_ * DM_, W2, DPROJ_, 2176, DM_);
        {
            dim3 g(ROWS_ / 128, 2176 / 128, 1);
            gemm_mfma_kernel<128,128><<<g, 256, 0, stream>>>(
                A2, W2, nullptr, nullptr, 0, nullptr,
                ZX, DPROJ_, nullptr, 0, ROWS_, DPROJ_, DM_, 0);
        }

        bcconv_kernel<<<(ROWS_ * 32 + 255) / 256, 256, 0, stream>>>(ZX, cwl, cbl, BCc);
        dt_kernel<<<(ROWS_ * NH_ + 255) / 256, 256, 0, stream>>>(
            ZX, dt_bias + (size_t)l * NH_, A_log + (size_t)l * NH_, DT, DA);

        scanA_kernel<<<NBLK, 64, 0, stream>>>(ZX, BCc, DT, DA, cwl, cbl, SCH, PCH, XWIN);
        scanB_kernel<<<B_ * NH_, 64, 0, stream>>>(SCH, PCH);
        scanC_kernel<<<NBLK, 64, 0, stream>>>(ZX, BCc, DT, DA, cwl, cbl,
                                              D_ssm + (size_t)l * NH_, SCH, XWIN);

        gatenorm_kernel<<<ROWS_, 256, 0, stream>>>(ZX, gnorm_w + (size_t)l * DI_);

        // ---- out_proj (split-K x2, 128x64 tiles -> partials -> reduce into X) ----
        convA_kernel<<<(ROWS_ * DI_ + 255) / 256, 256, 0, stream>>>(
            ZX + DI_, DPROJ_, A2, ROWS_, DI_);
        convW_kernel<<<(DM_ * DI_ + 255) / 256, 256, 0, stream>>>(
            out_proj_w + (size_t)l * DM_ * DI_, W2, DM_, DM_, DI_);
        {
            dim3 g(ROWS_ / 128, DM_ / 64, 2);
            gemm_mfma_kernel<128,64><<<g, 256, 0, stream>>>(
                A2, W2, nullptr, nullptr, 0, PART_OP,
                nullptr, 0, nullptr, 0, ROWS_, DM_, DI_, 0);
        }
        reduceK_kernel<<<(ROWS_ * DM_ / 4 + 255) / 256, 256, 0, stream>>>(
            PART_OP, nullptr, X, ROWS_ * DM_);

        // ---- ffn: fused norm+convert, ffn1 (128x128) emits bf16 split hidden, ffn2 split-K ----
        convAN_kernel<<<ROWS_, 64, 0, stream>>>(X, norm_ffn_w + (size_t)l * DM_, A2);
        convW_kernel<<<(DFF_ * DM_ + 255) / 256, 256, 0, stream>>>(
            ffn_w1 + (size_t)l * DFF_ * DM_, W2, DFF_, DFF_, DM_);
        {
            dim3 g(ROWS_ / 128, DFF_ / 128, 1);
            gemm_mfma_kernel<128,128><<<g, 256, 0, stream>>>(
                A2, W2, ffn_b1 + (size_t)l * DFF_, nullptr, 0, nullptr,
                nullptr, 0, Hs, DFF_, ROWS_, DFF_, DM_, 1);
        }
        convW_kernel<<<(DM_ * DFF_ + 255) / 256, 256, 0, stream>>>(
            ffn_w2 + (size_t)l * DM_ * DFF_, W2, DM_, DM_, DFF_);
        {
            dim3 g(ROWS_ / 128, DM_ / 64, 2);
            gemm_mfma_kernel<128,64><<<g, 256, 0, stream>>>(
                Hs, W2, nullptr, nullptr, 0, PART_F2,
                nullptr, 0, nullptr, 0, ROWS_, DM_, DFF_, 0);
        }
        reduceK_kernel<<<(ROWS_ * DM_ / 4 + 255) / 256, 256, 0, stream>>>(
            PART_F2, ffn_b2 + (size_t)l * DM_, X, ROWS_ * DM_);
    }

    finalnorm_kernel<<<ROWS_, 256, 0, stream>>>(X, final_norm_w, (float*)d_out);
}